// Round 1
// baseline (1297.696 us; speedup 1.0000x reference)
//
#include <hip/hip_runtime.h>
#include <hip/hip_bf16.h>

// Problem constants
#define B2    2
#define C     512
#define HH    128
#define WW    128
#define HW    16384
#define HEADS 64

typedef __attribute__((ext_vector_type(8))) short bf16x8;
typedef __attribute__((ext_vector_type(4))) float f32x4;

__device__ __forceinline__ float b2f(short s) {
    union { unsigned u; float f; } x;
    x.u = ((unsigned)(unsigned short)s) << 16;
    return x.f;
}
// Native bf16 convert (RNE): compiler emits v_cvt_pk_bf16_f32 for pairs.
// Hand-rolled integer RNE (bfe+add3+shift, ~4 VALU/value) was the staging
// bottleneck in k_gemm.
__device__ __forceinline__ short f2b(float f) {
    __hip_bfloat16 h = __float2bfloat16(f);
    short s; __builtin_memcpy(&s, &h, 2); return s;
}

// ---------------------------------------------------------------------------
// Vectorized 3x3 depthwise conv for one channel, 8 consecutive pixels/thread.
// Thread layout: 16 lanes span one 128-px row (col0 = (lane&15)*8). Column
// halo via __shfl from lane+-1 (vector end elements); row halo via zeroed
// payload (uniform shuffles). 'SAME' zero padding at image borders.
// ---------------------------------------------------------------------------
__device__ __forceinline__ void conv8(
    const short* __restrict__ plane, int row, int lane, int cg,
    const float* __restrict__ w9, float bias0, float* o)
{
    #pragma unroll
    for (int i = 0; i < 8; ++i) o[i] = bias0;
    #pragma unroll
    for (int dr = 0; dr < 3; ++dr) {
        const int r2 = row + dr - 1;
        const bool ok = (unsigned)r2 < (unsigned)HH;
        bf16x8 v = {0, 0, 0, 0, 0, 0, 0, 0};
        if (ok) v = *(const bf16x8*)(plane + (size_t)r2 * WW);
        float rv[10];
        #pragma unroll
        for (int j = 0; j < 8; ++j) rv[1 + j] = b2f(v[j]);
        const float lf = __shfl(rv[8], lane - 1);   // neighbor's col0+7 = my col0-1
        const float rt = __shfl(rv[1], lane + 1);   // neighbor's col0   = my col0+8
        rv[0] = (cg == 0)  ? 0.f : lf;
        rv[9] = (cg == 15) ? 0.f : rt;
        const float w0 = w9[dr * 3], w1 = w9[dr * 3 + 1], w2 = w9[dr * 3 + 2];
        #pragma unroll
        for (int i = 0; i < 8; ++i)
            o[i] += w0 * rv[i] + w1 * rv[i + 1] + w2 * rv[i + 2];
    }
}

// ---------------------------------------------------------------------------
// K1: 1x1 conv as GEMM. fp32 -> bf16 at staging (v_cvt_pk path), MFMA
// 16x16x32, bf16 output slab.
// ---------------------------------------------------------------------------
#define BM 128
#define BN 128
#define BK 32
#define LDK 40

struct GemmJob  { const float* X; const float* W; const float* bias; short* Y; int co_off; };
struct GemmJobs { GemmJob j[4]; };

__global__ __launch_bounds__(256) void k_gemm(GemmJobs jobs)
{
    __shared__ __align__(16) short As[BM * LDK];
    __shared__ __align__(16) short Bs[BN * LDK];

    const GemmJob jb = jobs.j[blockIdx.z];
    const float* X    = jb.X;
    const float* Wm   = jb.W;
    const float* bias = jb.bias;
    short*       Y    = jb.Y;
    const int co_off  = jb.co_off;

    const int co0 = blockIdx.x * BM;
    const int p0  = blockIdx.y * BN;

    const int t = threadIdx.x;
    const int lane = t & 63, wv = t >> 6;
    const int wm = (wv & 1) << 6, wn = (wv >> 1) << 6;
    const int l15 = lane & 15, quad = lane >> 4;
    const int rm = t & 127;
    const int kc = (t >> 7) << 4;

    f32x4 acc[4][4] = {};

    for (int kk = 0; kk < C; kk += BK) {
        const float* asrc = Wm + (size_t)(co_off + co0 + rm) * C + kk + kc;
        __align__(16) short abuf[16];
        #pragma unroll
        for (int j = 0; j < 4; ++j) {
            f32x4 v = *(const f32x4*)(asrc + j * 4);
            abuf[j * 4 + 0] = f2b(v[0]); abuf[j * 4 + 1] = f2b(v[1]);
            abuf[j * 4 + 2] = f2b(v[2]); abuf[j * 4 + 3] = f2b(v[3]);
        }
        const float* bsrc = X + (size_t)(kk + kc) * HW + p0 + rm;
        __align__(16) short tmp[16];
        #pragma unroll
        for (int j = 0; j < 16; ++j) tmp[j] = f2b(bsrc[(size_t)j * HW]);

        *(bf16x8*)&As[rm * LDK + kc]     = *(const bf16x8*)abuf;
        *(bf16x8*)&As[rm * LDK + kc + 8] = *(const bf16x8*)(abuf + 8);
        *(bf16x8*)&Bs[rm * LDK + kc]     = *(const bf16x8*)tmp;
        *(bf16x8*)&Bs[rm * LDK + kc + 8] = *(const bf16x8*)(tmp + 8);
        __syncthreads();

        bf16x8 af[4], bfr[4];
        #pragma unroll
        for (int i = 0; i < 4; ++i)
            af[i]  = *(const bf16x8*)&As[(wm + i * 16 + l15) * LDK + quad * 8];
        #pragma unroll
        for (int i = 0; i < 4; ++i)
            bfr[i] = *(const bf16x8*)&Bs[(wn + i * 16 + l15) * LDK + quad * 8];
        #pragma unroll
        for (int i = 0; i < 4; ++i)
            #pragma unroll
            for (int j = 0; j < 4; ++j)
                acc[i][j] = __builtin_amdgcn_mfma_f32_16x16x32_bf16(af[i], bfr[j], acc[i][j], 0, 0, 0);
        __syncthreads();
    }

    #pragma unroll
    for (int i = 0; i < 4; ++i) {
        #pragma unroll
        for (int r = 0; r < 4; ++r) {
            const int co = co0 + wm + i * 16 + quad * 4 + r;
            const float bv = bias[co_off + co];
            #pragma unroll
            for (int j = 0; j < 4; ++j) {
                const int p = p0 + wn + j * 16 + l15;
                Y[(size_t)co * HW + p] = f2b(acc[i][j][r] + bv);
            }
        }
    }
}

// ---------------------------------------------------------------------------
// K2: stats for one (batch, type), vectorized. Each thread: one 8-px group,
// all 8 q-channels (packed bf16) then 8 k-channels, S[8][8]+norms in regs,
// butterfly reduce, atomics.
// ---------------------------------------------------------------------------
__global__ __launch_bounds__(256) void k_stats(
    const short* __restrict__ qk,
    const float* __restrict__ dwh_w, const float* __restrict__ dwh_b,
    const float* __restrict__ dwl_w, const float* __restrict__ dwl_b,
    float* __restrict__ dot1, float* __restrict__ dot2, float* __restrict__ sumsq,
    int b, int type)
{
    __shared__ float wq[72], wk[72], bq[8], bk[8];
    const int chunk = blockIdx.x;     // 8 chunks of 16 rows
    const int h = blockIdx.y;

    const float* qdw = type ? dwl_w : dwh_w;
    const float* qdb = type ? dwl_b : dwh_b;
    const float* kdw = type ? dwh_w : dwl_w;
    const float* kdb = type ? dwh_b : dwl_b;

    const int t = threadIdx.x;
    if (t < 72) { wq[t] = qdw[h * 72 + t]; wk[t] = kdw[C * 9 + h * 72 + t]; }
    if (t < 8)  { bq[t] = qdb[h * 8 + t];  bk[t] = kdb[C + h * 8 + t]; }
    __syncthreads();

    const int lane = t & 63, cg = t & 15;
    const int row = chunk * 16 + (t >> 4);
    const int col0 = cg << 3;

    const short* qbase = qk + (size_t)(h * 8) * HW + col0;
    const short* kbase = qk + (size_t)(C + h * 8) * HW + col0;

    // Phase A: q channels -> packed bf16 + qq
    bf16x8 vq[8];
    float qq[8];
    #pragma unroll
    for (int d = 0; d < 8; ++d) {
        float o[8];
        conv8(qbase + (size_t)d * HW, row, lane, cg, wq + d * 9, bq[d], o);
        float s2 = 0.f;
        bf16x8 pk;
        #pragma unroll
        for (int px = 0; px < 8; ++px) { s2 += o[px] * o[px]; pk[px] = f2b(o[px]); }
        qq[d] = s2;
        vq[d] = pk;
    }

    // Phase B: k channels -> S, kq
    float S[8][8];
    float kq[8];
    #pragma unroll
    for (int j = 0; j < 8; ++j) {
        float o[8];
        conv8(kbase + (size_t)j * HW, row, lane, cg, wk + j * 9, bk[j], o);
        float s2 = 0.f;
        #pragma unroll
        for (int px = 0; px < 8; ++px) s2 += o[px] * o[px];
        kq[j] = s2;
        #pragma unroll
        for (int i = 0; i < 8; ++i) {
            float a = 0.f;
            #pragma unroll
            for (int px = 0; px < 8; ++px) a += b2f(vq[i][px]) * o[px];
            S[i][j] = a;
        }
    }

    // wave butterfly reduce + one atomic per wave per value
    float* dotp = (type ? dot2 : dot1) + ((size_t)(b * HEADS + h) << 6);
    #pragma unroll
    for (int i = 0; i < 8; ++i) {
        #pragma unroll
        for (int j = 0; j < 8; ++j) {
            float v = S[i][j];
            v += __shfl_down(v, 32); v += __shfl_down(v, 16); v += __shfl_down(v, 8);
            v += __shfl_down(v, 4);  v += __shfl_down(v, 2);  v += __shfl_down(v, 1);
            if (lane == 0) atomicAdd(&dotp[i * 8 + j], v);
        }
        float v1 = qq[i];
        v1 += __shfl_down(v1, 32); v1 += __shfl_down(v1, 16); v1 += __shfl_down(v1, 8);
        v1 += __shfl_down(v1, 4);  v1 += __shfl_down(v1, 2);  v1 += __shfl_down(v1, 1);
        float v2 = kq[i];
        v2 += __shfl_down(v2, 32); v2 += __shfl_down(v2, 16); v2 += __shfl_down(v2, 8);
        v2 += __shfl_down(v2, 4);  v2 += __shfl_down(v2, 2);  v2 += __shfl_down(v2, 1);
        if (lane == 0) {
            atomicAdd(&sumsq[((type * 2) * 2 + b) * C + h * 8 + i], v1);
            atomicAdd(&sumsq[((type * 2 + 1) * 2 + b) * C + h * 8 + i], v2);
        }
    }
}

// ---------------------------------------------------------------------------
// K3: attn normalize + temp, proj conv1x1 + BN + ReLU, softmax -> a1, a2
// ---------------------------------------------------------------------------
__global__ __launch_bounds__(256) void k_fuse(
    const float* __restrict__ dot1, const float* __restrict__ dot2,
    const float* __restrict__ sumsq,
    const float* __restrict__ temp1, const float* __restrict__ temp2,
    const float* __restrict__ pw, const float* __restrict__ pb,
    const float* __restrict__ g, const float* __restrict__ be,
    const float* __restrict__ mu, const float* __restrict__ var,
    float* __restrict__ a1, float* __restrict__ a2)
{
    __shared__ float cat[128 * 64];
    __shared__ float fus[64 * 64];
    const int b = blockIdx.x;
    const int t = threadIdx.x;
    const float EPS = 1e-12f;

    for (int idx = t; idx < 128 * 64; idx += 256) {
        const int ic = idx >> 6, ij = idx & 63, i = ij >> 3, j = ij & 7;
        const int is2 = ic >> 6, h = ic & 63;
        const float* dp = is2 ? dot2 : dot1;
        const int qkk = is2 * 2, kkk = is2 * 2 + 1;
        const float nq = sqrtf(sumsq[(qkk * 2 + b) * C + h * 8 + i]);
        const float nk = sqrtf(sumsq[(kkk * 2 + b) * C + h * 8 + j]);
        const float tv = is2 ? temp2[h] : temp1[h];
        const float d = dp[((size_t)(b * HEADS + h) << 6) + ij];
        cat[idx] = d / (fmaxf(nq, EPS) * fmaxf(nk, EPS)) * tv;
    }
    __syncthreads();

    for (int idx = t; idx < 64 * 64; idx += 256) {
        const int hd = idx >> 6, ij = idx & 63;
        float acc = pb[hd];
        for (int ic = 0; ic < 128; ++ic)
            acc += pw[hd * 128 + ic] * cat[ic * 64 + ij];
        const float sc = g[hd] / sqrtf(var[hd] + 1e-5f);
        const float v = (acc - mu[hd]) * sc + be[hd];
        fus[idx] = fmaxf(v, 0.f);
    }
    __syncthreads();

    for (int r = t; r < 512; r += 256) {
        const int hd = r >> 3, i = r & 7;
        float v[8], mx, sum;
        mx = -1e30f;
        #pragma unroll
        for (int j = 0; j < 8; ++j) { v[j] = fus[(hd << 6) + i * 8 + j] + cat[(hd << 6) + i * 8 + j]; mx = fmaxf(mx, v[j]); }
        sum = 0.f;
        #pragma unroll
        for (int j = 0; j < 8; ++j) { v[j] = __expf(v[j] - mx); sum += v[j]; }
        #pragma unroll
        for (int j = 0; j < 8; ++j) a1[((size_t)(b * HEADS + hd) << 6) + i * 8 + j] = v[j] / sum;
        mx = -1e30f;
        #pragma unroll
        for (int j = 0; j < 8; ++j) { v[j] = fus[(hd << 6) + i * 8 + j] + cat[((64 + hd) << 6) + i * 8 + j]; mx = fmaxf(mx, v[j]); }
        sum = 0.f;
        #pragma unroll
        for (int j = 0; j < 8; ++j) { v[j] = __expf(v[j] - mx); sum += v[j]; }
        #pragma unroll
        for (int j = 0; j < 8; ++j) a2[((size_t)(b * HEADS + hd) << 6) + i * 8 + j] = v[j] / sum;
    }
}

// ---------------------------------------------------------------------------
// K4: output, vectorized. dwconv(v) per thread (8 px x 8 ch in regs),
// out[i] = x[i] + v[i] + sum_d A[i][d]*v[d], f32x4 loads/stores.
// __launch_bounds__(256,3): cap VGPR at 170 -> 3 waves/SIMD (was 200 -> 2);
// kernel is latency-bound (occ 10%, 1.88 TB/s vs 37 us BW floor).
// ---------------------------------------------------------------------------
__global__ __launch_bounds__(256, 3) void k_out(
    const short* __restrict__ v,
    const float* __restrict__ hsi, const float* __restrict__ lidar,
    const float* __restrict__ dwh_w, const float* __restrict__ dwh_b,
    const float* __restrict__ dwl_w, const float* __restrict__ dwl_b,
    const float* __restrict__ a1, const float* __restrict__ a2,
    float* __restrict__ out)
{
    __shared__ float A[64];
    __shared__ float wv[72], bvs[8];
    const int chunk = blockIdx.x, h = blockIdx.y, zb = blockIdx.z;
    const int s = zb >> 1, b = zb & 1;
    const int t = threadIdx.x;

    const float* x   = (s ? lidar : hsi) + (size_t)b * C * HW;
    const float* dww = s ? dwl_w : dwh_w;
    const float* dwb = s ? dwl_b : dwh_b;
    const float* Ag  = (s ? a2 : a1) + ((size_t)(b * HEADS + h) << 6);
    if (t < 64) A[t] = Ag[t];
    if (t < 72) wv[t] = dww[(2 * C + h * 8) * 9 + t];
    if (t < 8)  bvs[t] = dwb[2 * C + h * 8 + t];
    __syncthreads();

    const int lane = t & 63, cg = t & 15;
    const int row = chunk * 16 + (t >> 4);
    const int col0 = cg << 3;

    const short* ybase = v + ((size_t)(zb * 512 + h * 8)) * HW + col0;
    const float* xbase = x + (size_t)(h * 8) * HW + (size_t)row * WW + col0;
    float* obase = out + ((size_t)((s * B2 + b) * C + h * 8)) * HW + (size_t)row * WW + col0;

    float vv[8][8];
    #pragma unroll
    for (int d = 0; d < 8; ++d)
        conv8(ybase + (size_t)d * HW, row, lane, cg, wv + d * 9, bvs[d], vv[d]);

    #pragma unroll
    for (int i = 0; i < 8; ++i) {
        f32x4 x0 = *(const f32x4*)(xbase + (size_t)i * HW);
        f32x4 x1 = *(const f32x4*)(xbase + (size_t)i * HW + 4);
        float o[8];
        #pragma unroll
        for (int px = 0; px < 8; ++px)
            o[px] = vv[i][px] + (px < 4 ? x0[px & 3] : x1[px & 3]);
        #pragma unroll
        for (int d = 0; d < 8; ++d) {
            const float ad = A[i * 8 + d];
            #pragma unroll
            for (int px = 0; px < 8; ++px) o[px] += ad * vv[d][px];
        }
        f32x4 o0 = { o[0], o[1], o[2], o[3] };
        f32x4 o1 = { o[4], o[5], o[6], o[7] };
        *(f32x4*)(obase + (size_t)i * HW)     = o0;
        *(f32x4*)(obase + (size_t)i * HW + 4) = o1;
    }
}

// ---------------------------------------------------------------------------
extern "C" void kernel_launch(void* const* d_in, const int* in_sizes, int n_in,
                              void* d_out, int out_size, void* d_ws, size_t ws_size,
                              hipStream_t stream)
{
    const float* hsi  = (const float*)d_in[0];
    const float* lidar= (const float*)d_in[1];
    const float* hqw  = (const float*)d_in[2];
    const float* hqb  = (const float*)d_in[3];
    const float* lqw  = (const float*)d_in[4];
    const float* lqb  = (const float*)d_in[5];
    const float* hdw  = (const float*)d_in[6];
    const float* hdb  = (const float*)d_in[7];
    const float* ldw  = (const float*)d_in[8];
    const float* ldb  = (const float*)d_in[9];
    const float* t1   = (const float*)d_in[10];
    const float* t2   = (const float*)d_in[11];
    const float* pw   = (const float*)d_in[12];
    const float* pb   = (const float*)d_in[13];
    const float* bg   = (const float*)d_in[14];
    const float* bb   = (const float*)d_in[15];
    const float* bm   = (const float*)d_in[16];
    const float* bvv  = (const float*)d_in[17];

    // Workspace: [0,147456) fp32 stats; [147456, +32 MiB) bf16 slab. ~33.7 MB.
    char* ws = (char*)d_ws;
    float* dot1  = (float*)ws;                               // [2][64][8][8]
    float* dot2  = dot1 + 2 * HEADS * 64;
    float* sumsq = dot2 + 2 * HEADS * 64;                    // [4][2][512]
    float* a1    = sumsq + 4 * 2 * C;
    float* a2    = a1 + 2 * HEADS * 64;
    short* slab  = (short*)(ws + 147456);                    // 32 MiB

    const size_t statbytes = (size_t)(2 * HEADS * 64 * 2 + 4 * 2 * C) * sizeof(float);
    hipMemsetAsync(dot1, 0, statbytes, stream);

    // Phase 1: per (batch, type): GEMM q-stream q + k-stream k, then stats.
    for (int b = 0; b < 2; ++b) {
        for (int type = 0; type < 2; ++type) {
            const float* qx = (type ? lidar : hsi) + (size_t)b * C * HW;
            const float* kx = (type ? hsi : lidar) + (size_t)b * C * HW;
            const float* qw = type ? lqw : hqw;  const float* qb = type ? lqb : hqb;
            const float* kw = type ? hqw : lqw;  const float* kb = type ? hqb : lqb;
            GemmJobs jj;
            jj.j[0] = { qx, qw, qb, slab,                    0 };   // q: W rows [0,512)
            jj.j[1] = { kx, kw, kb, slab + (size_t)C * HW,   C };   // k: W rows [512,1024)
            jj.j[2] = jj.j[0]; jj.j[3] = jj.j[0];
            k_gemm<<<dim3(4, 128, 2), 256, 0, stream>>>(jj);
            k_stats<<<dim3(8, 64, 1), 256, 0, stream>>>(
                slab, hdw, hdb, ldw, ldb, dot1, dot2, sumsq, b, type);
        }
    }

    // Phase 2: GEMM v for all 4 (s,b) into slab (reused).
    GemmJobs vj;
    vj.j[0] = { hsi,                      hqw, hqb, slab,                        2 * C };
    vj.j[1] = { hsi   + (size_t)C * HW,   hqw, hqb, slab + (size_t)C * HW,       2 * C };
    vj.j[2] = { lidar,                    lqw, lqb, slab + (size_t)2 * C * HW,   2 * C };
    vj.j[3] = { lidar + (size_t)C * HW,   lqw, lqb, slab + (size_t)3 * C * HW,   2 * C };
    k_gemm<<<dim3(4, 128, 4), 256, 0, stream>>>(vj);

    // Phase 3: fuse scores -> a1,a2 ; Phase 4: outputs.
    k_fuse<<<dim3(2, 1, 1), 256, 0, stream>>>(dot1, dot2, sumsq, t1, t2,
                                              pw, pb, bg, bb, bm, bvv, a1, a2);
    k_out<<<dim3(8, 64, 4), 256, 0, stream>>>(slab, hsi, lidar,
                                              hdw, hdb, ldw, ldb, a1, a2,
                                              (float*)d_out);
}

// Round 2
// 1025.916 us; speedup vs baseline: 1.2649x; 1.2649x over previous
//
#include <hip/hip_runtime.h>
#include <hip/hip_bf16.h>

// Problem constants
#define B2    2
#define C     512
#define HH    128
#define WW    128
#define HW    16384
#define HEADS 64

typedef __attribute__((ext_vector_type(8))) short bf16x8;
typedef __attribute__((ext_vector_type(4))) float f32x4;
typedef __attribute__((ext_vector_type(4))) unsigned u32x4;

__device__ __forceinline__ float b2f(short s) {
    union { unsigned u; float f; } x;
    x.u = ((unsigned)(unsigned short)s) << 16;
    return x.f;
}
// Integer RNE (used only in low-frequency epilogue paths).
__device__ __forceinline__ short f2b(float f) {
    unsigned u; __builtin_memcpy(&u, &f, 4);
    unsigned r = u + 0x7FFFu + ((u >> 16) & 1u);   // RNE
    return (short)(r >> 16);
}
// HW packed conversion: 2 f32 -> 1 dword of 2 bf16 (RNE), one VALU op.
// (m240: no builtin on gfx950; m214v22 verified this asm form.)
__device__ __forceinline__ unsigned cvt_pk(float lo, float hi) {
    unsigned r;
    asm("v_cvt_pk_bf16_f32 %0, %1, %2" : "=v"(r) : "v"(lo), "v"(hi));
    return r;
}

// ---------------------------------------------------------------------------
// Vectorized 3x3 depthwise conv for one channel, 8 consecutive pixels/thread.
// Thread layout: 16 lanes span one 128-px row (col0 = (lane&15)*8). Column
// halo via __shfl from lane+-1 (vector end elements); row halo via zeroed
// payload (uniform shuffles). 'SAME' zero padding at image borders.
// ---------------------------------------------------------------------------
__device__ __forceinline__ void conv8(
    const short* __restrict__ plane, int row, int lane, int cg,
    const float* __restrict__ w9, float bias0, float* o)
{
    #pragma unroll
    for (int i = 0; i < 8; ++i) o[i] = bias0;
    #pragma unroll
    for (int dr = 0; dr < 3; ++dr) {
        const int r2 = row + dr - 1;
        const bool ok = (unsigned)r2 < (unsigned)HH;
        bf16x8 v = {0, 0, 0, 0, 0, 0, 0, 0};
        if (ok) v = *(const bf16x8*)(plane + (size_t)r2 * WW);
        float rv[10];
        #pragma unroll
        for (int j = 0; j < 8; ++j) rv[1 + j] = b2f(v[j]);
        const float lf = __shfl(rv[8], lane - 1);   // neighbor's col0+7 = my col0-1
        const float rt = __shfl(rv[1], lane + 1);   // neighbor's col0   = my col0+8
        rv[0] = (cg == 0)  ? 0.f : lf;
        rv[9] = (cg == 15) ? 0.f : rt;
        const float w0 = w9[dr * 3], w1 = w9[dr * 3 + 1], w2 = w9[dr * 3 + 2];
        #pragma unroll
        for (int i = 0; i < 8; ++i)
            o[i] += w0 * rv[i] + w1 * rv[i + 1] + w2 * rv[i + 2];
    }
}

// ---------------------------------------------------------------------------
// K1: 1x1 conv as GEMM. fp32 -> bf16 at staging via v_cvt_pk_bf16_f32
// (1 instr / 2 elems; was ~3.5 VALU/elem integer RNE). MFMA 16x16x32,
// bf16 output slab.
// ---------------------------------------------------------------------------
#define BM 128
#define BN 128
#define BK 32
#define LDK 40

struct GemmJob  { const float* X; const float* W; const float* bias; short* Y; int co_off; };
struct GemmJobs { GemmJob j[8]; };

__global__ __launch_bounds__(256) void k_gemm(GemmJobs jobs)
{
    __shared__ __align__(16) short As[BM * LDK];
    __shared__ __align__(16) short Bs[BN * LDK];

    const GemmJob jb = jobs.j[blockIdx.z];
    const float* X    = jb.X;
    const float* Wm   = jb.W;
    const float* bias = jb.bias;
    short*       Y    = jb.Y;
    const int co_off  = jb.co_off;

    const int co0 = blockIdx.x * BM;
    const int p0  = blockIdx.y * BN;

    const int t = threadIdx.x;
    const int lane = t & 63, wv = t >> 6;
    const int wm = (wv & 1) << 6, wn = (wv >> 1) << 6;
    const int l15 = lane & 15, quad = lane >> 4;
    const int rm = t & 127;
    const int kc = (t >> 7) << 4;

    f32x4 acc[4][4] = {};

    for (int kk = 0; kk < C; kk += BK) {
        const float* asrc = Wm + (size_t)(co_off + co0 + rm) * C + kk + kc;
        unsigned au[4];
        #pragma unroll
        for (int j = 0; j < 2; ++j) {
            f32x4 v = *(const f32x4*)(asrc + j * 4);
            au[2 * j]     = cvt_pk(v[0], v[1]);
            au[2 * j + 1] = cvt_pk(v[2], v[3]);
        }
        unsigned au2[4];
        #pragma unroll
        for (int j = 0; j < 2; ++j) {
            f32x4 v = *(const f32x4*)(asrc + 8 + j * 4);
            au2[2 * j]     = cvt_pk(v[0], v[1]);
            au2[2 * j + 1] = cvt_pk(v[2], v[3]);
        }
        const float* bsrc = X + (size_t)(kk + kc) * HW + p0 + rm;
        float bv[16];
        #pragma unroll
        for (int j = 0; j < 16; ++j) bv[j] = bsrc[(size_t)j * HW];
        unsigned bu[8];
        #pragma unroll
        for (int j = 0; j < 8; ++j) bu[j] = cvt_pk(bv[2 * j], bv[2 * j + 1]);

        *(u32x4*)&As[rm * LDK + kc]     = *(const u32x4*)au;
        *(u32x4*)&As[rm * LDK + kc + 8] = *(const u32x4*)au2;
        *(u32x4*)&Bs[rm * LDK + kc]     = *(const u32x4*)bu;
        *(u32x4*)&Bs[rm * LDK + kc + 8] = *(const u32x4*)(bu + 4);
        __syncthreads();

        bf16x8 af[4], bfr[4];
        #pragma unroll
        for (int i = 0; i < 4; ++i)
            af[i]  = *(const bf16x8*)&As[(wm + i * 16 + l15) * LDK + quad * 8];
        #pragma unroll
        for (int i = 0; i < 4; ++i)
            bfr[i] = *(const bf16x8*)&Bs[(wn + i * 16 + l15) * LDK + quad * 8];
        #pragma unroll
        for (int i = 0; i < 4; ++i)
            #pragma unroll
            for (int j = 0; j < 4; ++j)
                acc[i][j] = __builtin_amdgcn_mfma_f32_16x16x32_bf16(af[i], bfr[j], acc[i][j], 0, 0, 0);
        __syncthreads();
    }

    #pragma unroll
    for (int i = 0; i < 4; ++i) {
        #pragma unroll
        for (int r = 0; r < 4; ++r) {
            const int co = co0 + wm + i * 16 + quad * 4 + r;
            const float bv = bias[co_off + co];
            #pragma unroll
            for (int j = 0; j < 4; ++j) {
                const int p = p0 + wn + j * 16 + l15;
                Y[(size_t)co * HW + p] = f2b(acc[i][j][r] + bv);
            }
        }
    }
}

// ---------------------------------------------------------------------------
// K2: stats for one (batch, type) job, vectorized. Each thread: one 8-px
// group, all 8 q-channels (packed bf16 via cvt_pk) then 8 k-channels,
// S[8][8]+norms in regs, butterfly reduce, atomics.
// Job selection: job = job0 + blockIdx.z; qk = qk0 + jobstride*blockIdx.z.
// ---------------------------------------------------------------------------
__global__ __launch_bounds__(256) void k_stats(
    const short* __restrict__ qk0,
    const float* __restrict__ dwh_w, const float* __restrict__ dwh_b,
    const float* __restrict__ dwl_w, const float* __restrict__ dwl_b,
    float* __restrict__ dot1, float* __restrict__ dot2, float* __restrict__ sumsq,
    int job0, long long jobstride)
{
    __shared__ float wq[72], wk[72], bq[8], bk[8];
    const int chunk = blockIdx.x;     // 8 chunks of 16 rows
    const int h = blockIdx.y;
    const int job = job0 + blockIdx.z;
    const int b = job >> 1, type = job & 1;
    const short* qk = qk0 + (size_t)jobstride * blockIdx.z;

    const float* qdw = type ? dwl_w : dwh_w;
    const float* qdb = type ? dwl_b : dwh_b;
    const float* kdw = type ? dwh_w : dwl_w;
    const float* kdb = type ? dwh_b : dwl_b;

    const int t = threadIdx.x;
    if (t < 72) { wq[t] = qdw[h * 72 + t]; wk[t] = kdw[C * 9 + h * 72 + t]; }
    if (t < 8)  { bq[t] = qdb[h * 8 + t];  bk[t] = kdb[C + h * 8 + t]; }
    __syncthreads();

    const int lane = t & 63, cg = t & 15;
    const int row = chunk * 16 + (t >> 4);
    const int col0 = cg << 3;

    const short* qbase = qk + (size_t)(h * 8) * HW + col0;
    const short* kbase = qk + (size_t)(C + h * 8) * HW + col0;

    // Phase A: q channels -> packed bf16 + qq
    bf16x8 vq[8];
    float qq[8];
    #pragma unroll
    for (int d = 0; d < 8; ++d) {
        float o[8];
        conv8(qbase + (size_t)d * HW, row, lane, cg, wq + d * 9, bq[d], o);
        float s2 = 0.f;
        #pragma unroll
        for (int px = 0; px < 8; ++px) s2 += o[px] * o[px];
        qq[d] = s2;
        unsigned pu[4];
        #pragma unroll
        for (int p = 0; p < 4; ++p) pu[p] = cvt_pk(o[2 * p], o[2 * p + 1]);
        bf16x8 pkv; __builtin_memcpy(&pkv, pu, 16);
        vq[d] = pkv;
    }

    // Phase B: k channels -> S, kq
    float S[8][8];
    float kq[8];
    #pragma unroll
    for (int j = 0; j < 8; ++j) {
        float o[8];
        conv8(kbase + (size_t)j * HW, row, lane, cg, wk + j * 9, bk[j], o);
        float s2 = 0.f;
        #pragma unroll
        for (int px = 0; px < 8; ++px) s2 += o[px] * o[px];
        kq[j] = s2;
        #pragma unroll
        for (int i = 0; i < 8; ++i) {
            float a = 0.f;
            #pragma unroll
            for (int px = 0; px < 8; ++px) a += b2f(vq[i][px]) * o[px];
            S[i][j] = a;
        }
    }

    // wave butterfly reduce + one atomic per wave per value
    float* dotp = (type ? dot2 : dot1) + ((size_t)(b * HEADS + h) << 6);
    #pragma unroll
    for (int i = 0; i < 8; ++i) {
        #pragma unroll
        for (int j = 0; j < 8; ++j) {
            float v = S[i][j];
            v += __shfl_down(v, 32); v += __shfl_down(v, 16); v += __shfl_down(v, 8);
            v += __shfl_down(v, 4);  v += __shfl_down(v, 2);  v += __shfl_down(v, 1);
            if (lane == 0) atomicAdd(&dotp[i * 8 + j], v);
        }
        float v1 = qq[i];
        v1 += __shfl_down(v1, 32); v1 += __shfl_down(v1, 16); v1 += __shfl_down(v1, 8);
        v1 += __shfl_down(v1, 4);  v1 += __shfl_down(v1, 2);  v1 += __shfl_down(v1, 1);
        float v2 = kq[i];
        v2 += __shfl_down(v2, 32); v2 += __shfl_down(v2, 16); v2 += __shfl_down(v2, 8);
        v2 += __shfl_down(v2, 4);  v2 += __shfl_down(v2, 2);  v2 += __shfl_down(v2, 1);
        if (lane == 0) {
            atomicAdd(&sumsq[((type * 2) * 2 + b) * C + h * 8 + i], v1);
            atomicAdd(&sumsq[((type * 2 + 1) * 2 + b) * C + h * 8 + i], v2);
        }
    }
}

// ---------------------------------------------------------------------------
// K3: attn normalize + temp, proj conv1x1 + BN + ReLU, softmax -> a1, a2
// ---------------------------------------------------------------------------
__global__ __launch_bounds__(256) void k_fuse(
    const float* __restrict__ dot1, const float* __restrict__ dot2,
    const float* __restrict__ sumsq,
    const float* __restrict__ temp1, const float* __restrict__ temp2,
    const float* __restrict__ pw, const float* __restrict__ pb,
    const float* __restrict__ g, const float* __restrict__ be,
    const float* __restrict__ mu, const float* __restrict__ var,
    float* __restrict__ a1, float* __restrict__ a2)
{
    __shared__ float cat[128 * 64];
    __shared__ float fus[64 * 64];
    const int b = blockIdx.x;
    const int t = threadIdx.x;
    const float EPS = 1e-12f;

    for (int idx = t; idx < 128 * 64; idx += 256) {
        const int ic = idx >> 6, ij = idx & 63, i = ij >> 3, j = ij & 7;
        const int is2 = ic >> 6, h = ic & 63;
        const float* dp = is2 ? dot2 : dot1;
        const int qkk = is2 * 2, kkk = is2 * 2 + 1;
        const float nq = sqrtf(sumsq[(qkk * 2 + b) * C + h * 8 + i]);
        const float nk = sqrtf(sumsq[(kkk * 2 + b) * C + h * 8 + j]);
        const float tv = is2 ? temp2[h] : temp1[h];
        const float d = dp[((size_t)(b * HEADS + h) << 6) + ij];
        cat[idx] = d / (fmaxf(nq, EPS) * fmaxf(nk, EPS)) * tv;
    }
    __syncthreads();

    for (int idx = t; idx < 64 * 64; idx += 256) {
        const int hd = idx >> 6, ij = idx & 63;
        float acc = pb[hd];
        for (int ic = 0; ic < 128; ++ic)
            acc += pw[hd * 128 + ic] * cat[ic * 64 + ij];
        const float sc = g[hd] / sqrtf(var[hd] + 1e-5f);
        const float v = (acc - mu[hd]) * sc + be[hd];
        fus[idx] = fmaxf(v, 0.f);
    }
    __syncthreads();

    for (int r = t; r < 512; r += 256) {
        const int hd = r >> 3, i = r & 7;
        float v[8], mx, sum;
        mx = -1e30f;
        #pragma unroll
        for (int j = 0; j < 8; ++j) { v[j] = fus[(hd << 6) + i * 8 + j] + cat[(hd << 6) + i * 8 + j]; mx = fmaxf(mx, v[j]); }
        sum = 0.f;
        #pragma unroll
        for (int j = 0; j < 8; ++j) { v[j] = __expf(v[j] - mx); sum += v[j]; }
        #pragma unroll
        for (int j = 0; j < 8; ++j) a1[((size_t)(b * HEADS + hd) << 6) + i * 8 + j] = v[j] / sum;
        mx = -1e30f;
        #pragma unroll
        for (int j = 0; j < 8; ++j) { v[j] = fus[(hd << 6) + i * 8 + j] + cat[((64 + hd) << 6) + i * 8 + j]; mx = fmaxf(mx, v[j]); }
        sum = 0.f;
        #pragma unroll
        for (int j = 0; j < 8; ++j) { v[j] = __expf(v[j] - mx); sum += v[j]; }
        #pragma unroll
        for (int j = 0; j < 8; ++j) a2[((size_t)(b * HEADS + hd) << 6) + i * 8 + j] = v[j] / sum;
    }
}

// ---------------------------------------------------------------------------
// K4: output. RESTRUCTURED for register pressure: fold the +v identity into
// A (A'[i][d] = A[i][d] + delta_id), stream one conv channel vd at a time,
// accumulate into o[8][8]. Live set ~o[64]+vd[8]+conv temps (~120 VGPR)
// instead of vv[8][8]+o (~190) -> natural 3 waves/SIMD without forced cap
// (R1: __launch_bounds__(256,3) spilled, 4x HBM traffic, 268us).
// ---------------------------------------------------------------------------
__global__ __launch_bounds__(256) void k_out(
    const short* __restrict__ v,
    const float* __restrict__ hsi, const float* __restrict__ lidar,
    const float* __restrict__ dwh_w, const float* __restrict__ dwh_b,
    const float* __restrict__ dwl_w, const float* __restrict__ dwl_b,
    const float* __restrict__ a1, const float* __restrict__ a2,
    float* __restrict__ out)
{
    __shared__ float A[64];          // A' = A + I
    __shared__ float wv[72], bvs[8];
    const int chunk = blockIdx.x, h = blockIdx.y, zb = blockIdx.z;
    const int s = zb >> 1, b = zb & 1;
    const int t = threadIdx.x;

    const float* x   = (s ? lidar : hsi) + (size_t)b * C * HW;
    const float* dww = s ? dwl_w : dwh_w;
    const float* dwb = s ? dwl_b : dwh_b;
    const float* Ag  = (s ? a2 : a1) + ((size_t)(b * HEADS + h) << 6);
    if (t < 64) A[t] = Ag[t] + (((t >> 3) == (t & 7)) ? 1.0f : 0.0f);
    if (t < 72) wv[t] = dww[(2 * C + h * 8) * 9 + t];
    if (t < 8)  bvs[t] = dwb[2 * C + h * 8 + t];
    __syncthreads();

    const int lane = t & 63, cg = t & 15;
    const int row = chunk * 16 + (t >> 4);
    const int col0 = cg << 3;

    const short* ybase = v + ((size_t)(zb * 512 + h * 8)) * HW + col0;
    const float* xbase = x + (size_t)(h * 8) * HW + (size_t)row * WW + col0;
    float* obase = out + ((size_t)((s * B2 + b) * C + h * 8)) * HW + (size_t)row * WW + col0;

    float o[8][8];
    #pragma unroll
    for (int i = 0; i < 8; ++i)
        #pragma unroll
        for (int px = 0; px < 8; ++px) o[i][px] = 0.f;

    #pragma unroll
    for (int d = 0; d < 8; ++d) {
        float vd[8];
        conv8(ybase + (size_t)d * HW, row, lane, cg, wv + d * 9, bvs[d], vd);
        #pragma unroll
        for (int i = 0; i < 8; ++i) {
            const float ad = A[i * 8 + d];
            #pragma unroll
            for (int px = 0; px < 8; ++px) o[i][px] += ad * vd[px];
        }
    }

    #pragma unroll
    for (int i = 0; i < 8; ++i) {
        f32x4 x0 = *(const f32x4*)(xbase + (size_t)i * HW);
        f32x4 x1 = *(const f32x4*)(xbase + (size_t)i * HW + 4);
        f32x4 o0 = { o[i][0] + x0[0], o[i][1] + x0[1], o[i][2] + x0[2], o[i][3] + x0[3] };
        f32x4 o1 = { o[i][4] + x1[0], o[i][5] + x1[1], o[i][6] + x1[2], o[i][7] + x1[3] };
        *(f32x4*)(obase + (size_t)i * HW)     = o0;
        *(f32x4*)(obase + (size_t)i * HW + 4) = o1;
    }
}

// ---------------------------------------------------------------------------
extern "C" void kernel_launch(void* const* d_in, const int* in_sizes, int n_in,
                              void* d_out, int out_size, void* d_ws, size_t ws_size,
                              hipStream_t stream)
{
    const float* hsi  = (const float*)d_in[0];
    const float* lidar= (const float*)d_in[1];
    const float* hqw  = (const float*)d_in[2];
    const float* hqb  = (const float*)d_in[3];
    const float* lqw  = (const float*)d_in[4];
    const float* lqb  = (const float*)d_in[5];
    const float* hdw  = (const float*)d_in[6];
    const float* hdb  = (const float*)d_in[7];
    const float* ldw  = (const float*)d_in[8];
    const float* ldb  = (const float*)d_in[9];
    const float* t1   = (const float*)d_in[10];
    const float* t2   = (const float*)d_in[11];
    const float* pw   = (const float*)d_in[12];
    const float* pb   = (const float*)d_in[13];
    const float* bg   = (const float*)d_in[14];
    const float* bb   = (const float*)d_in[15];
    const float* bm   = (const float*)d_in[16];
    const float* bvv  = (const float*)d_in[17];

    // Workspace: [0,147456) fp32 stats; slab after that.
    char* ws = (char*)d_ws;
    float* dot1  = (float*)ws;                               // [2][64][8][8]
    float* dot2  = dot1 + 2 * HEADS * 64;
    float* sumsq = dot2 + 2 * HEADS * 64;                    // [4][2][512]
    float* a1    = sumsq + 4 * 2 * C;
    float* a2    = a1 + 2 * HEADS * 64;
    short* slab  = (short*)(ws + 147456);

    const size_t statbytes = (size_t)(2 * HEADS * 64 * 2 + 4 * 2 * C) * sizeof(float);
    hipMemsetAsync(dot1, 0, statbytes, stream);

    const size_t jobBytes = (size_t)C * HW * sizeof(short);  // 16.8 MB
    const size_t bigNeed  = 147456 + 8 * jobBytes;           // ~134.4 MB

    if (ws_size >= bigNeed) {
        // ---- Big-workspace path: 1 qk-GEMM launch (8 jobs), 1 stats launch
        // (z=4), 1 v-GEMM launch, fuse, out. 6 launches total.
        GemmJobs jj;
        for (int job = 0; job < 4; ++job) {
            const int b = job >> 1, type = job & 1;
            const float* qx = (type ? lidar : hsi) + (size_t)b * C * HW;
            const float* kx = (type ? hsi : lidar) + (size_t)b * C * HW;
            const float* qw = type ? lqw : hqw;  const float* qb = type ? lqb : hqb;
            const float* kw = type ? hqw : lqw;  const float* kb = type ? hqb : lqb;
            jj.j[2 * job]     = { qx, qw, qb, slab + (size_t)(2 * job) * C * HW,     0 };
            jj.j[2 * job + 1] = { kx, kw, kb, slab + (size_t)(2 * job + 1) * C * HW, C };
        }
        k_gemm<<<dim3(4, 128, 8), 256, 0, stream>>>(jj);
        k_stats<<<dim3(8, 64, 4), 256, 0, stream>>>(
            slab, hdw, hdb, ldw, ldb, dot1, dot2, sumsq,
            0, (long long)(2 * (size_t)C * HW));

        GemmJobs vj;
        vj.j[0] = { hsi,                    hqw, hqb, slab,                      2 * C };
        vj.j[1] = { hsi   + (size_t)C * HW, hqw, hqb, slab + (size_t)C * HW,     2 * C };
        vj.j[2] = { lidar,                  lqw, lqb, slab + (size_t)2 * C * HW, 2 * C };
        vj.j[3] = { lidar + (size_t)C * HW, lqw, lqb, slab + (size_t)3 * C * HW, 2 * C };
        for (int i = 4; i < 8; ++i) vj.j[i] = vj.j[0];
        k_gemm<<<dim3(4, 128, 4), 256, 0, stream>>>(vj);
    } else {
        // ---- Fallback (known-good sequencing, ~34 MB workspace) ----
        for (int b = 0; b < 2; ++b) {
            for (int type = 0; type < 2; ++type) {
                const float* qx = (type ? lidar : hsi) + (size_t)b * C * HW;
                const float* kx = (type ? hsi : lidar) + (size_t)b * C * HW;
                const float* qw = type ? lqw : hqw;  const float* qb = type ? lqb : hqb;
                const float* kw = type ? hqw : lqw;  const float* kb = type ? hqb : lqb;
                GemmJobs jj;
                jj.j[0] = { qx, qw, qb, slab,                  0 };
                jj.j[1] = { kx, kw, kb, slab + (size_t)C * HW, C };
                for (int i = 2; i < 8; ++i) jj.j[i] = jj.j[0];
                k_gemm<<<dim3(4, 128, 2), 256, 0, stream>>>(jj);
                k_stats<<<dim3(8, 64, 1), 256, 0, stream>>>(
                    slab, hdw, hdb, ldw, ldb, dot1, dot2, sumsq,
                    b * 2 + type, 0LL);
            }
        }
        GemmJobs vj;
        vj.j[0] = { hsi,                    hqw, hqb, slab,                      2 * C };
        vj.j[1] = { hsi   + (size_t)C * HW, hqw, hqb, slab + (size_t)C * HW,     2 * C };
        vj.j[2] = { lidar,                  lqw, lqb, slab + (size_t)2 * C * HW, 2 * C };
        vj.j[3] = { lidar + (size_t)C * HW, lqw, lqb, slab + (size_t)3 * C * HW, 2 * C };
        for (int i = 4; i < 8; ++i) vj.j[i] = vj.j[0];
        k_gemm<<<dim3(4, 128, 4), 256, 0, stream>>>(vj);
    }

    // Phase 3: fuse scores -> a1,a2 ; Phase 4: outputs.
    k_fuse<<<dim3(2, 1, 1), 256, 0, stream>>>(dot1, dot2, sumsq, t1, t2,
                                              pw, pb, bg, bb, bm, bvv, a1, a2);
    k_out<<<dim3(8, 64, 4), 256, 0, stream>>>(slab, hsi, lidar,
                                              hdw, hdb, ldw, ldb, a1, a2,
                                              (float*)d_out);
}

// Round 3
// 853.872 us; speedup vs baseline: 1.5198x; 1.2015x over previous
//
#include <hip/hip_runtime.h>
#include <hip/hip_bf16.h>

// Problem constants
#define B2    2
#define C     512
#define HH    128
#define WW    128
#define HW    16384
#define HEADS 64

typedef __attribute__((ext_vector_type(8))) short bf16x8;
typedef __attribute__((ext_vector_type(4))) float f32x4;
typedef __attribute__((ext_vector_type(4))) unsigned u32x4;

__device__ __forceinline__ float b2f(short s) {
    union { unsigned u; float f; } x;
    x.u = ((unsigned)(unsigned short)s) << 16;
    return x.f;
}
// Integer RNE (used only in low-frequency epilogue paths).
__device__ __forceinline__ short f2b(float f) {
    unsigned u; __builtin_memcpy(&u, &f, 4);
    unsigned r = u + 0x7FFFu + ((u >> 16) & 1u);   // RNE
    return (short)(r >> 16);
}
// HW packed conversion: 2 f32 -> 1 dword of 2 bf16 (RNE), one VALU op.
__device__ __forceinline__ unsigned cvt_pk(float lo, float hi) {
    unsigned r;
    asm("v_cvt_pk_bf16_f32 %0, %1, %2" : "=v"(r) : "v"(lo), "v"(hi));
    return r;
}

// ---------------------------------------------------------------------------
// Vectorized 3x3 depthwise conv for one channel, 8 consecutive pixels/thread.
// Thread layout: 16 lanes span one 128-px row (col0 = (lane&15)*8). Column
// halo via __shfl from lane+-1; row halo via zeroed payload.
// (Used by k_out.)
// ---------------------------------------------------------------------------
__device__ __forceinline__ void conv8(
    const short* __restrict__ plane, int row, int lane, int cg,
    const float* __restrict__ w9, float bias0, float* o)
{
    #pragma unroll
    for (int i = 0; i < 8; ++i) o[i] = bias0;
    #pragma unroll
    for (int dr = 0; dr < 3; ++dr) {
        const int r2 = row + dr - 1;
        const bool ok = (unsigned)r2 < (unsigned)HH;
        bf16x8 v = {0, 0, 0, 0, 0, 0, 0, 0};
        if (ok) v = *(const bf16x8*)(plane + (size_t)r2 * WW);
        float rv[10];
        #pragma unroll
        for (int j = 0; j < 8; ++j) rv[1 + j] = b2f(v[j]);
        const float lf = __shfl(rv[8], lane - 1);   // neighbor's col0+7 = my col0-1
        const float rt = __shfl(rv[1], lane + 1);   // neighbor's col0   = my col0+8
        rv[0] = (cg == 0)  ? 0.f : lf;
        rv[9] = (cg == 15) ? 0.f : rt;
        const float w0 = w9[dr * 3], w1 = w9[dr * 3 + 1], w2 = w9[dr * 3 + 2];
        #pragma unroll
        for (int i = 0; i < 8; ++i)
            o[i] += w0 * rv[i] + w1 * rv[i + 1] + w2 * rv[i + 2];
    }
}

// ---------------------------------------------------------------------------
// K1: 1x1 conv as GEMM. fp32 -> bf16 at staging via v_cvt_pk_bf16_f32.
// MFMA 16x16x32, bf16 output slab. (Unchanged from R2.)
// ---------------------------------------------------------------------------
#define BM 128
#define BN 128
#define BK 32
#define LDK 40

struct GemmJob  { const float* X; const float* W; const float* bias; short* Y; int co_off; };
struct GemmJobs { GemmJob j[8]; };

__global__ __launch_bounds__(256) void k_gemm(GemmJobs jobs)
{
    __shared__ __align__(16) short As[BM * LDK];
    __shared__ __align__(16) short Bs[BN * LDK];

    const GemmJob jb = jobs.j[blockIdx.z];
    const float* X    = jb.X;
    const float* Wm   = jb.W;
    const float* bias = jb.bias;
    short*       Y    = jb.Y;
    const int co_off  = jb.co_off;

    const int co0 = blockIdx.x * BM;
    const int p0  = blockIdx.y * BN;

    const int t = threadIdx.x;
    const int lane = t & 63, wv = t >> 6;
    const int wm = (wv & 1) << 6, wn = (wv >> 1) << 6;
    const int l15 = lane & 15, quad = lane >> 4;
    const int rm = t & 127;
    const int kc = (t >> 7) << 4;

    f32x4 acc[4][4] = {};

    for (int kk = 0; kk < C; kk += BK) {
        const float* asrc = Wm + (size_t)(co_off + co0 + rm) * C + kk + kc;
        unsigned au[4];
        #pragma unroll
        for (int j = 0; j < 2; ++j) {
            f32x4 v = *(const f32x4*)(asrc + j * 4);
            au[2 * j]     = cvt_pk(v[0], v[1]);
            au[2 * j + 1] = cvt_pk(v[2], v[3]);
        }
        unsigned au2[4];
        #pragma unroll
        for (int j = 0; j < 2; ++j) {
            f32x4 v = *(const f32x4*)(asrc + 8 + j * 4);
            au2[2 * j]     = cvt_pk(v[0], v[1]);
            au2[2 * j + 1] = cvt_pk(v[2], v[3]);
        }
        const float* bsrc = X + (size_t)(kk + kc) * HW + p0 + rm;
        float bv[16];
        #pragma unroll
        for (int j = 0; j < 16; ++j) bv[j] = bsrc[(size_t)j * HW];
        unsigned bu[8];
        #pragma unroll
        for (int j = 0; j < 8; ++j) bu[j] = cvt_pk(bv[2 * j], bv[2 * j + 1]);

        *(u32x4*)&As[rm * LDK + kc]     = *(const u32x4*)au;
        *(u32x4*)&As[rm * LDK + kc + 8] = *(const u32x4*)au2;
        *(u32x4*)&Bs[rm * LDK + kc]     = *(const u32x4*)bu;
        *(u32x4*)&Bs[rm * LDK + kc + 8] = *(const u32x4*)(bu + 4);
        __syncthreads();

        bf16x8 af[4], bfr[4];
        #pragma unroll
        for (int i = 0; i < 4; ++i)
            af[i]  = *(const bf16x8*)&As[(wm + i * 16 + l15) * LDK + quad * 8];
        #pragma unroll
        for (int i = 0; i < 4; ++i)
            bfr[i] = *(const bf16x8*)&Bs[(wn + i * 16 + l15) * LDK + quad * 8];
        #pragma unroll
        for (int i = 0; i < 4; ++i)
            #pragma unroll
            for (int j = 0; j < 4; ++j)
                acc[i][j] = __builtin_amdgcn_mfma_f32_16x16x32_bf16(af[i], bfr[j], acc[i][j], 0, 0, 0);
        __syncthreads();
    }

    #pragma unroll
    for (int i = 0; i < 4; ++i) {
        #pragma unroll
        for (int r = 0; r < 4; ++r) {
            const int co = co0 + wm + i * 16 + quad * 4 + r;
            const float bv = bias[co_off + co];
            #pragma unroll
            for (int j = 0; j < 4; ++j) {
                const int p = p0 + wn + j * 16 + l15;
                Y[(size_t)co * HW + p] = f2b(acc[i][j][r] + bv);
            }
        }
    }
}

// ---------------------------------------------------------------------------
// K2 REWRITE: Gram matrix via MFMA. Per (job, head) stack G = [q0..q7,
// k0..k7] (16 ch x HW px). G.G^T computed with mfma_f32_16x16x32_bf16 where
// the SAME fragment serves as A and B (A: row=lane&15, k=(lane>>4)*8+e;
// B: col=lane&15, same k -> identical lane data for a symmetric Gram).
// Lane = (channel = lane&15, px-group = lane>>4): ONE conv8 per lane per
// 32-px chunk (was 16 convs/thread), no bf16 re-unpack, no 6-deep shfl
// butterflies. S = Gram rows 0-7 x cols 8-15 -> 4 predicated atomics/wave.
// Norms stay f32 (per-lane sumsq + 2 shfl + 1 atomic) to match previous
// precision. Halo loaded directly (2B scalar loads) instead of shfl.
// ---------------------------------------------------------------------------
__global__ __launch_bounds__(256) void k_stats(
    const short* __restrict__ qk0,
    const float* __restrict__ dwh_w, const float* __restrict__ dwh_b,
    const float* __restrict__ dwl_w, const float* __restrict__ dwl_b,
    float* __restrict__ dot1, float* __restrict__ dot2, float* __restrict__ sumsq,
    int job0, long long jobstride)
{
    const int chunk = blockIdx.x;     // 8 chunks of 16 rows
    const int h = blockIdx.y;
    const int job = job0 + blockIdx.z;
    const int b = job >> 1, type = job & 1;
    const short* qk = qk0 + (size_t)jobstride * blockIdx.z;

    const int t = threadIdx.x;
    const int lane = t & 63, w = t >> 6;
    const int ch = lane & 15, g = lane >> 4;
    const bool isq = (ch < 8);

    // Per-lane depthwise weights + bias (9 f32 in regs, loaded once).
    const float* dw = isq ? (type ? dwl_w : dwh_w) : (type ? dwh_w : dwl_w);
    const float* db = isq ? (type ? dwl_b : dwh_b) : (type ? dwh_b : dwl_b);
    const int crow = isq ? (h * 8 + ch) : (C + h * 8 + ch - 8);
    float w9[9];
    #pragma unroll
    for (int i = 0; i < 9; ++i) w9[i] = dw[crow * 9 + i];
    const float bias0 = db[crow];

    // Source plane for this lane's channel within the job's qk slab.
    const short* plane = qk + (size_t)(isq ? (h * 8 + ch)
                                           : (C + h * 8 + ch - 8)) * HW;

    f32x4 acc = {0.f, 0.f, 0.f, 0.f};
    float s2 = 0.f;

    for (int cr = 0; cr < 4; ++cr) {
        const int row = chunk * 16 + w * 4 + cr;
        #pragma unroll
        for (int cc = 0; cc < 4; ++cc) {
            const int px0 = cc * 32 + g * 8;
            float o[8];
            #pragma unroll
            for (int i = 0; i < 8; ++i) o[i] = bias0;
            #pragma unroll
            for (int dr = 0; dr < 3; ++dr) {
                const int r2 = row + dr - 1;
                const bool ok = (unsigned)r2 < (unsigned)HH;
                const short* rp = plane + (size_t)r2 * WW;
                bf16x8 v = {0, 0, 0, 0, 0, 0, 0, 0};
                short sl = 0, sr = 0;
                if (ok) {
                    v = *(const bf16x8*)(rp + px0);
                    if (px0 > 0)      sl = rp[px0 - 1];
                    if (px0 + 8 < WW) sr = rp[px0 + 8];
                }
                float rv[10];
                rv[0] = b2f(sl); rv[9] = b2f(sr);
                #pragma unroll
                for (int j = 0; j < 8; ++j) rv[1 + j] = b2f(v[j]);
                const float w0 = w9[dr * 3], w1 = w9[dr * 3 + 1], w2 = w9[dr * 3 + 2];
                #pragma unroll
                for (int i = 0; i < 8; ++i)
                    o[i] += w0 * rv[i] + w1 * rv[i + 1] + w2 * rv[i + 2];
            }
            #pragma unroll
            for (int i = 0; i < 8; ++i) s2 += o[i] * o[i];
            unsigned pu[4];
            #pragma unroll
            for (int p = 0; p < 4; ++p) pu[p] = cvt_pk(o[2 * p], o[2 * p + 1]);
            bf16x8 f; __builtin_memcpy(&f, pu, 16);
            acc = __builtin_amdgcn_mfma_f32_16x16x32_bf16(f, f, acc, 0, 0, 0);
        }
    }

    // S entries: Gram rows 0-7 (q), cols 8-15 (k). C-layout: lane holds
    // D[g*4+r][ch], r=0..3 (m89: col=lane&15, row=(lane>>4)*4+reg).
    float* dotp = (type ? dot2 : dot1) + ((size_t)(b * HEADS + h) << 6);
    #pragma unroll
    for (int r = 0; r < 4; ++r) {
        const int rowc = g * 4 + r;
        if (rowc < 8 && ch >= 8)
            atomicAdd(&dotp[rowc * 8 + (ch - 8)], acc[r]);
    }
    // Norms: lanes {l, l+16, l+32, l+48} share a channel.
    s2 += __shfl_down(s2, 32);
    s2 += __shfl_down(s2, 16);
    if (g == 0) {
        float* sp = isq
            ? &sumsq[((type * 2) * 2 + b) * C + h * 8 + ch]
            : &sumsq[((type * 2 + 1) * 2 + b) * C + h * 8 + (ch - 8)];
        atomicAdd(sp, s2);
    }
}

// ---------------------------------------------------------------------------
// K3: attn normalize + temp, proj conv1x1 + BN + ReLU, softmax -> a1, a2
// ---------------------------------------------------------------------------
__global__ __launch_bounds__(256) void k_fuse(
    const float* __restrict__ dot1, const float* __restrict__ dot2,
    const float* __restrict__ sumsq,
    const float* __restrict__ temp1, const float* __restrict__ temp2,
    const float* __restrict__ pw, const float* __restrict__ pb,
    const float* __restrict__ g, const float* __restrict__ be,
    const float* __restrict__ mu, const float* __restrict__ var,
    float* __restrict__ a1, float* __restrict__ a2)
{
    __shared__ float cat[128 * 64];
    __shared__ float fus[64 * 64];
    const int b = blockIdx.x;
    const int t = threadIdx.x;
    const float EPS = 1e-12f;

    for (int idx = t; idx < 128 * 64; idx += 256) {
        const int ic = idx >> 6, ij = idx & 63, i = ij >> 3, j = ij & 7;
        const int is2 = ic >> 6, h = ic & 63;
        const float* dp = is2 ? dot2 : dot1;
        const int qkk = is2 * 2, kkk = is2 * 2 + 1;
        const float nq = sqrtf(sumsq[(qkk * 2 + b) * C + h * 8 + i]);
        const float nk = sqrtf(sumsq[(kkk * 2 + b) * C + h * 8 + j]);
        const float tv = is2 ? temp2[h] : temp1[h];
        const float d = dp[((size_t)(b * HEADS + h) << 6) + ij];
        cat[idx] = d / (fmaxf(nq, EPS) * fmaxf(nk, EPS)) * tv;
    }
    __syncthreads();

    for (int idx = t; idx < 64 * 64; idx += 256) {
        const int hd = idx >> 6, ij = idx & 63;
        float acc = pb[hd];
        for (int ic = 0; ic < 128; ++ic)
            acc += pw[hd * 128 + ic] * cat[ic * 64 + ij];
        const float sc = g[hd] / sqrtf(var[hd] + 1e-5f);
        const float v = (acc - mu[hd]) * sc + be[hd];
        fus[idx] = fmaxf(v, 0.f);
    }
    __syncthreads();

    for (int r = t; r < 512; r += 256) {
        const int hd = r >> 3, i = r & 7;
        float v[8], mx, sum;
        mx = -1e30f;
        #pragma unroll
        for (int j = 0; j < 8; ++j) { v[j] = fus[(hd << 6) + i * 8 + j] + cat[(hd << 6) + i * 8 + j]; mx = fmaxf(mx, v[j]); }
        sum = 0.f;
        #pragma unroll
        for (int j = 0; j < 8; ++j) { v[j] = __expf(v[j] - mx); sum += v[j]; }
        #pragma unroll
        for (int j = 0; j < 8; ++j) a1[((size_t)(b * HEADS + hd) << 6) + i * 8 + j] = v[j] / sum;
        mx = -1e30f;
        #pragma unroll
        for (int j = 0; j < 8; ++j) { v[j] = fus[(hd << 6) + i * 8 + j] + cat[((64 + hd) << 6) + i * 8 + j]; mx = fmaxf(mx, v[j]); }
        sum = 0.f;
        #pragma unroll
        for (int j = 0; j < 8; ++j) { v[j] = __expf(v[j] - mx); sum += v[j]; }
        #pragma unroll
        for (int j = 0; j < 8; ++j) a2[((size_t)(b * HEADS + hd) << 6) + i * 8 + j] = v[j] / sum;
    }
}

// ---------------------------------------------------------------------------
// K4: output. Fold the +v identity into A (A' = A + I), stream one conv
// channel at a time into o[8][8]. (Unchanged from R2.)
// ---------------------------------------------------------------------------
__global__ __launch_bounds__(256) void k_out(
    const short* __restrict__ v,
    const float* __restrict__ hsi, const float* __restrict__ lidar,
    const float* __restrict__ dwh_w, const float* __restrict__ dwh_b,
    const float* __restrict__ dwl_w, const float* __restrict__ dwl_b,
    const float* __restrict__ a1, const float* __restrict__ a2,
    float* __restrict__ out)
{
    __shared__ float A[64];          // A' = A + I
    __shared__ float wv[72], bvs[8];
    const int chunk = blockIdx.x, h = blockIdx.y, zb = blockIdx.z;
    const int s = zb >> 1, b = zb & 1;
    const int t = threadIdx.x;

    const float* x   = (s ? lidar : hsi) + (size_t)b * C * HW;
    const float* dww = s ? dwl_w : dwh_w;
    const float* dwb = s ? dwl_b : dwh_b;
    const float* Ag  = (s ? a2 : a1) + ((size_t)(b * HEADS + h) << 6);
    if (t < 64) A[t] = Ag[t] + (((t >> 3) == (t & 7)) ? 1.0f : 0.0f);
    if (t < 72) wv[t] = dww[(2 * C + h * 8) * 9 + t];
    if (t < 8)  bvs[t] = dwb[2 * C + h * 8 + t];
    __syncthreads();

    const int lane = t & 63, cg = t & 15;
    const int row = chunk * 16 + (t >> 4);
    const int col0 = cg << 3;

    const short* ybase = v + ((size_t)(zb * 512 + h * 8)) * HW + col0;
    const float* xbase = x + (size_t)(h * 8) * HW + (size_t)row * WW + col0;
    float* obase = out + ((size_t)((s * B2 + b) * C + h * 8)) * HW + (size_t)row * WW + col0;

    float o[8][8];
    #pragma unroll
    for (int i = 0; i < 8; ++i)
        #pragma unroll
        for (int px = 0; px < 8; ++px) o[i][px] = 0.f;

    #pragma unroll
    for (int d = 0; d < 8; ++d) {
        float vd[8];
        conv8(ybase + (size_t)d * HW, row, lane, cg, wv + d * 9, bvs[d], vd);
        #pragma unroll
        for (int i = 0; i < 8; ++i) {
            const float ad = A[i * 8 + d];
            #pragma unroll
            for (int px = 0; px < 8; ++px) o[i][px] += ad * vd[px];
        }
    }

    #pragma unroll
    for (int i = 0; i < 8; ++i) {
        f32x4 x0 = *(const f32x4*)(xbase + (size_t)i * HW);
        f32x4 x1 = *(const f32x4*)(xbase + (size_t)i * HW + 4);
        f32x4 o0 = { o[i][0] + x0[0], o[i][1] + x0[1], o[i][2] + x0[2], o[i][3] + x0[3] };
        f32x4 o1 = { o[i][4] + x1[0], o[i][5] + x1[1], o[i][6] + x1[2], o[i][7] + x1[3] };
        *(f32x4*)(obase + (size_t)i * HW)     = o0;
        *(f32x4*)(obase + (size_t)i * HW + 4) = o1;
    }
}

// ---------------------------------------------------------------------------
extern "C" void kernel_launch(void* const* d_in, const int* in_sizes, int n_in,
                              void* d_out, int out_size, void* d_ws, size_t ws_size,
                              hipStream_t stream)
{
    const float* hsi  = (const float*)d_in[0];
    const float* lidar= (const float*)d_in[1];
    const float* hqw  = (const float*)d_in[2];
    const float* hqb  = (const float*)d_in[3];
    const float* lqw  = (const float*)d_in[4];
    const float* lqb  = (const float*)d_in[5];
    const float* hdw  = (const float*)d_in[6];
    const float* hdb  = (const float*)d_in[7];
    const float* ldw  = (const float*)d_in[8];
    const float* ldb  = (const float*)d_in[9];
    const float* t1   = (const float*)d_in[10];
    const float* t2   = (const float*)d_in[11];
    const float* pw   = (const float*)d_in[12];
    const float* pb   = (const float*)d_in[13];
    const float* bg   = (const float*)d_in[14];
    const float* bb   = (const float*)d_in[15];
    const float* bm   = (const float*)d_in[16];
    const float* bvv  = (const float*)d_in[17];

    // Workspace: [0,147456) fp32 stats; slab after that.
    char* ws = (char*)d_ws;
    float* dot1  = (float*)ws;                               // [2][64][8][8]
    float* dot2  = dot1 + 2 * HEADS * 64;
    float* sumsq = dot2 + 2 * HEADS * 64;                    // [4][2][512]
    float* a1    = sumsq + 4 * 2 * C;
    float* a2    = a1 + 2 * HEADS * 64;
    short* slab  = (short*)(ws + 147456);

    const size_t statbytes = (size_t)(2 * HEADS * 64 * 2 + 4 * 2 * C) * sizeof(float);
    hipMemsetAsync(dot1, 0, statbytes, stream);

    const size_t jobBytes = (size_t)C * HW * sizeof(short);  // 16.8 MB
    const size_t bigNeed  = 147456 + 8 * jobBytes;           // ~134.4 MB

    if (ws_size >= bigNeed) {
        // ---- Big-workspace path: 1 qk-GEMM launch (8 jobs), 1 stats launch
        // (z=4), 1 v-GEMM launch, fuse, out.
        GemmJobs jj;
        for (int job = 0; job < 4; ++job) {
            const int b = job >> 1, type = job & 1;
            const float* qx = (type ? lidar : hsi) + (size_t)b * C * HW;
            const float* kx = (type ? hsi : lidar) + (size_t)b * C * HW;
            const float* qw = type ? lqw : hqw;  const float* qb = type ? lqb : hqb;
            const float* kw = type ? hqw : lqw;  const float* kb = type ? hqb : lqb;
            jj.j[2 * job]     = { qx, qw, qb, slab + (size_t)(2 * job) * C * HW,     0 };
            jj.j[2 * job + 1] = { kx, kw, kb, slab + (size_t)(2 * job + 1) * C * HW, C };
        }
        k_gemm<<<dim3(4, 128, 8), 256, 0, stream>>>(jj);
        k_stats<<<dim3(8, 64, 4), 256, 0, stream>>>(
            slab, hdw, hdb, ldw, ldb, dot1, dot2, sumsq,
            0, (long long)(2 * (size_t)C * HW));

        GemmJobs vj;
        vj.j[0] = { hsi,                    hqw, hqb, slab,                      2 * C };
        vj.j[1] = { hsi   + (size_t)C * HW, hqw, hqb, slab + (size_t)C * HW,     2 * C };
        vj.j[2] = { lidar,                  lqw, lqb, slab + (size_t)2 * C * HW, 2 * C };
        vj.j[3] = { lidar + (size_t)C * HW, lqw, lqb, slab + (size_t)3 * C * HW, 2 * C };
        for (int i = 4; i < 8; ++i) vj.j[i] = vj.j[0];
        k_gemm<<<dim3(4, 128, 4), 256, 0, stream>>>(vj);
    } else {
        // ---- Fallback (known-good sequencing, ~34 MB workspace) ----
        for (int b = 0; b < 2; ++b) {
            for (int type = 0; type < 2; ++type) {
                const float* qx = (type ? lidar : hsi) + (size_t)b * C * HW;
                const float* kx = (type ? hsi : lidar) + (size_t)b * C * HW;
                const float* qw = type ? lqw : hqw;  const float* qb = type ? lqb : hqb;
                const float* kw = type ? hqw : lqw;  const float* kb = type ? hqb : lqb;
                GemmJobs jj;
                jj.j[0] = { qx, qw, qb, slab,                  0 };
                jj.j[1] = { kx, kw, kb, slab + (size_t)C * HW, C };
                for (int i = 2; i < 8; ++i) jj.j[i] = jj.j[0];
                k_gemm<<<dim3(4, 128, 2), 256, 0, stream>>>(jj);
                k_stats<<<dim3(8, 64, 1), 256, 0, stream>>>(
                    slab, hdw, hdb, ldw, ldb, dot1, dot2, sumsq,
                    b * 2 + type, 0LL);
            }
        }
        GemmJobs vj;
        vj.j[0] = { hsi,                    hqw, hqb, slab,                      2 * C };
        vj.j[1] = { hsi   + (size_t)C * HW, hqw, hqb, slab + (size_t)C * HW,     2 * C };
        vj.j[2] = { lidar,                  lqw, lqb, slab + (size_t)2 * C * HW, 2 * C };
        vj.j[3] = { lidar + (size_t)C * HW, lqw, lqb, slab + (size_t)3 * C * HW, 2 * C };
        for (int i = 4; i < 8; ++i) vj.j[i] = vj.j[0];
        k_gemm<<<dim3(4, 128, 4), 256, 0, stream>>>(vj);
    }

    // Phase 3: fuse scores -> a1,a2 ; Phase 4: outputs.
    k_fuse<<<dim3(2, 1, 1), 256, 0, stream>>>(dot1, dot2, sumsq, t1, t2,
                                              pw, pb, bg, bb, bm, bvv, a1, a2);
    k_out<<<dim3(8, 64, 4), 256, 0, stream>>>(slab, hsi, lidar,
                                              hdw, hdb, ldw, ldb, a1, a2,
                                              (float*)d_out);
}

// Round 4
// 843.960 us; speedup vs baseline: 1.5376x; 1.0117x over previous
//
#include <hip/hip_runtime.h>
#include <hip/hip_bf16.h>

// Problem constants
#define B2    2
#define C     512
#define HH    128
#define WW    128
#define HW    16384
#define HEADS 64

typedef __attribute__((ext_vector_type(8))) short bf16x8;
typedef __attribute__((ext_vector_type(4))) float f32x4;
typedef __attribute__((ext_vector_type(4))) unsigned u32x4;

__device__ __forceinline__ float b2f(short s) {
    union { unsigned u; float f; } x;
    x.u = ((unsigned)(unsigned short)s) << 16;
    return x.f;
}
// Integer RNE (used only in low-frequency epilogue paths).
__device__ __forceinline__ short f2b(float f) {
    unsigned u; __builtin_memcpy(&u, &f, 4);
    unsigned r = u + 0x7FFFu + ((u >> 16) & 1u);   // RNE
    return (short)(r >> 16);
}
// HW packed conversion: 2 f32 -> 1 dword of 2 bf16 (RNE), one VALU op.
__device__ __forceinline__ unsigned cvt_pk(float lo, float hi) {
    unsigned r;
    asm("v_cvt_pk_bf16_f32 %0, %1, %2" : "=v"(r) : "v"(lo), "v"(hi));
    return r;
}

// ---------------------------------------------------------------------------
// Vectorized 3x3 depthwise conv for one channel, 8 consecutive pixels/thread.
// (Used by k_out.)
// ---------------------------------------------------------------------------
__device__ __forceinline__ void conv8(
    const short* __restrict__ plane, int row, int lane, int cg,
    const float* __restrict__ w9, float bias0, float* o)
{
    #pragma unroll
    for (int i = 0; i < 8; ++i) o[i] = bias0;
    #pragma unroll
    for (int dr = 0; dr < 3; ++dr) {
        const int r2 = row + dr - 1;
        const bool ok = (unsigned)r2 < (unsigned)HH;
        bf16x8 v = {0, 0, 0, 0, 0, 0, 0, 0};
        if (ok) v = *(const bf16x8*)(plane + (size_t)r2 * WW);
        float rv[10];
        #pragma unroll
        for (int j = 0; j < 8; ++j) rv[1 + j] = b2f(v[j]);
        const float lf = __shfl(rv[8], lane - 1);   // neighbor's col0+7 = my col0-1
        const float rt = __shfl(rv[1], lane + 1);   // neighbor's col0   = my col0+8
        rv[0] = (cg == 0)  ? 0.f : lf;
        rv[9] = (cg == 15) ? 0.f : rt;
        const float w0 = w9[dr * 3], w1 = w9[dr * 3 + 1], w2 = w9[dr * 3 + 2];
        #pragma unroll
        for (int i = 0; i < 8; ++i)
            o[i] += w0 * rv[i] + w1 * rv[i + 1] + w2 * rv[i + 2];
    }
}

// ---------------------------------------------------------------------------
// K1: 1x1 conv as GEMM. fp32 -> bf16 at staging via v_cvt_pk_bf16_f32.
// MFMA 16x16x32, bf16 output slab.
// NEW (R4): bijective XCD swizzle (m204) so consecutive logical tiles
// (= co-blocks sharing one X tile) run on the SAME XCD; combined with
// merged q/k/v jobs (each image read ONCE vs 3x) this cuts the 4x HBM
// over-fetch seen in R3 (FETCH 538 MB vs 142 MB distinct).
// ---------------------------------------------------------------------------
#define BM 128
#define BN 128
#define BK 32
#define LDK 40

struct GemmJob  { const float* X; const float* W; const float* bias; short* Y; int co_off; };
struct GemmJobs { GemmJob j[8]; };

__global__ __launch_bounds__(256) void k_gemm(GemmJobs jobs)
{
    __shared__ __align__(16) short As[BM * LDK];
    __shared__ __align__(16) short Bs[BN * LDK];

    // XCD-aware remap: HW dispatches linear id round-robin across 8 XCDs;
    // lid = (hw%8)*(nwg/8) + hw/8 gives each XCD a CONTIGUOUS logical range,
    // so the gridDim.x co-blocks of one (y,z) tile share an XCD/L2.
    unsigned bx = blockIdx.x, by = blockIdx.y, bz = blockIdx.z;
    {
        const unsigned nx = gridDim.x, ny = gridDim.y, nz = gridDim.z;
        const unsigned nwg = nx * ny * nz;
        if ((nwg & 7u) == 0u) {
            const unsigned hw = bx + nx * (by + ny * bz);
            const unsigned lid = (hw & 7u) * (nwg >> 3) + (hw >> 3);
            bx = lid % nx;
            const unsigned rest = lid / nx;
            by = rest % ny;
            bz = rest / ny;
        }
    }

    const GemmJob jb = jobs.j[bz];
    const float* X    = jb.X;
    const float* Wm   = jb.W;
    const float* bias = jb.bias;
    short*       Y    = jb.Y;
    const int co_off  = jb.co_off;

    const int co0 = bx * BM;
    const int p0  = by * BN;

    const int t = threadIdx.x;
    const int lane = t & 63, wv = t >> 6;
    const int wm = (wv & 1) << 6, wn = (wv >> 1) << 6;
    const int l15 = lane & 15, quad = lane >> 4;
    const int rm = t & 127;
    const int kc = (t >> 7) << 4;

    f32x4 acc[4][4] = {};

    for (int kk = 0; kk < C; kk += BK) {
        const float* asrc = Wm + (size_t)(co_off + co0 + rm) * C + kk + kc;
        unsigned au[4];
        #pragma unroll
        for (int j = 0; j < 2; ++j) {
            f32x4 v = *(const f32x4*)(asrc + j * 4);
            au[2 * j]     = cvt_pk(v[0], v[1]);
            au[2 * j + 1] = cvt_pk(v[2], v[3]);
        }
        unsigned au2[4];
        #pragma unroll
        for (int j = 0; j < 2; ++j) {
            f32x4 v = *(const f32x4*)(asrc + 8 + j * 4);
            au2[2 * j]     = cvt_pk(v[0], v[1]);
            au2[2 * j + 1] = cvt_pk(v[2], v[3]);
        }
        const float* bsrc = X + (size_t)(kk + kc) * HW + p0 + rm;
        float bv[16];
        #pragma unroll
        for (int j = 0; j < 16; ++j) bv[j] = bsrc[(size_t)j * HW];
        unsigned bu[8];
        #pragma unroll
        for (int j = 0; j < 8; ++j) bu[j] = cvt_pk(bv[2 * j], bv[2 * j + 1]);

        *(u32x4*)&As[rm * LDK + kc]     = *(const u32x4*)au;
        *(u32x4*)&As[rm * LDK + kc + 8] = *(const u32x4*)au2;
        *(u32x4*)&Bs[rm * LDK + kc]     = *(const u32x4*)bu;
        *(u32x4*)&Bs[rm * LDK + kc + 8] = *(const u32x4*)(bu + 4);
        __syncthreads();

        bf16x8 af[4], bfr[4];
        #pragma unroll
        for (int i = 0; i < 4; ++i)
            af[i]  = *(const bf16x8*)&As[(wm + i * 16 + l15) * LDK + quad * 8];
        #pragma unroll
        for (int i = 0; i < 4; ++i)
            bfr[i] = *(const bf16x8*)&Bs[(wn + i * 16 + l15) * LDK + quad * 8];
        #pragma unroll
        for (int i = 0; i < 4; ++i)
            #pragma unroll
            for (int j = 0; j < 4; ++j)
                acc[i][j] = __builtin_amdgcn_mfma_f32_16x16x32_bf16(af[i], bfr[j], acc[i][j], 0, 0, 0);
        __syncthreads();
    }

    #pragma unroll
    for (int i = 0; i < 4; ++i) {
        #pragma unroll
        for (int r = 0; r < 4; ++r) {
            const int co = co0 + wm + i * 16 + quad * 4 + r;
            const float bv = bias[co_off + co];
            #pragma unroll
            for (int j = 0; j < 4; ++j) {
                const int p = p0 + wn + j * 16 + l15;
                Y[(size_t)co * HW + p] = f2b(acc[i][j][r] + bv);
            }
        }
    }
}

// ---------------------------------------------------------------------------
// K2: Gram matrix via MFMA (R3 structure). Parameterized q/k base pointers
// per z-job so it works with both the merged-qkv slab layout and fallbacks.
// ---------------------------------------------------------------------------
struct StatsJobs { const short* q[4]; const short* k[4]; };

__global__ __launch_bounds__(256) void k_stats(
    StatsJobs sj,
    const float* __restrict__ dwh_w, const float* __restrict__ dwh_b,
    const float* __restrict__ dwl_w, const float* __restrict__ dwl_b,
    float* __restrict__ dot1, float* __restrict__ dot2, float* __restrict__ sumsq,
    int job0)
{
    const int chunk = blockIdx.x;     // 8 chunks of 16 rows
    const int h = blockIdx.y;
    const int z = blockIdx.z;
    const int job = job0 + z;
    const int b = job >> 1, type = job & 1;

    const int t = threadIdx.x;
    const int lane = t & 63, w = t >> 6;
    const int ch = lane & 15, g = lane >> 4;
    const bool isq = (ch < 8);

    // Per-lane depthwise weights + bias (9 f32 in regs, loaded once).
    const float* dw = isq ? (type ? dwl_w : dwh_w) : (type ? dwh_w : dwl_w);
    const float* db = isq ? (type ? dwl_b : dwh_b) : (type ? dwh_b : dwl_b);
    const int crow = isq ? (h * 8 + ch) : (C + h * 8 + ch - 8);
    float w9[9];
    #pragma unroll
    for (int i = 0; i < 9; ++i) w9[i] = dw[crow * 9 + i];
    const float bias0 = db[crow];

    // Source plane for this lane's channel.
    const short* plane = isq ? (sj.q[z] + (size_t)(h * 8 + ch) * HW)
                             : (sj.k[z] + (size_t)(h * 8 + (ch - 8)) * HW);

    f32x4 acc = {0.f, 0.f, 0.f, 0.f};
    float s2 = 0.f;

    for (int cr = 0; cr < 4; ++cr) {
        const int row = chunk * 16 + w * 4 + cr;
        #pragma unroll
        for (int cc = 0; cc < 4; ++cc) {
            const int px0 = cc * 32 + g * 8;
            float o[8];
            #pragma unroll
            for (int i = 0; i < 8; ++i) o[i] = bias0;
            #pragma unroll
            for (int dr = 0; dr < 3; ++dr) {
                const int r2 = row + dr - 1;
                const bool ok = (unsigned)r2 < (unsigned)HH;
                const short* rp = plane + (size_t)r2 * WW;
                bf16x8 v = {0, 0, 0, 0, 0, 0, 0, 0};
                short sl = 0, sr = 0;
                if (ok) {
                    v = *(const bf16x8*)(rp + px0);
                    if (px0 > 0)      sl = rp[px0 - 1];
                    if (px0 + 8 < WW) sr = rp[px0 + 8];
                }
                float rv[10];
                rv[0] = b2f(sl); rv[9] = b2f(sr);
                #pragma unroll
                for (int j = 0; j < 8; ++j) rv[1 + j] = b2f(v[j]);
                const float w0 = w9[dr * 3], w1 = w9[dr * 3 + 1], w2 = w9[dr * 3 + 2];
                #pragma unroll
                for (int i = 0; i < 8; ++i)
                    o[i] += w0 * rv[i] + w1 * rv[i + 1] + w2 * rv[i + 2];
            }
            #pragma unroll
            for (int i = 0; i < 8; ++i) s2 += o[i] * o[i];
            unsigned pu[4];
            #pragma unroll
            for (int p = 0; p < 4; ++p) pu[p] = cvt_pk(o[2 * p], o[2 * p + 1]);
            bf16x8 f; __builtin_memcpy(&f, pu, 16);
            acc = __builtin_amdgcn_mfma_f32_16x16x32_bf16(f, f, acc, 0, 0, 0);
        }
    }

    // S entries: Gram rows 0-7 (q), cols 8-15 (k). C-layout (m89):
    // col=lane&15, row=(lane>>4)*4+reg.
    float* dotp = (type ? dot2 : dot1) + ((size_t)(b * HEADS + h) << 6);
    #pragma unroll
    for (int r = 0; r < 4; ++r) {
        const int rowc = g * 4 + r;
        if (rowc < 8 && ch >= 8)
            atomicAdd(&dotp[rowc * 8 + (ch - 8)], acc[r]);
    }
    // Norms: lanes {l, l+16, l+32, l+48} share a channel.
    s2 += __shfl_down(s2, 32);
    s2 += __shfl_down(s2, 16);
    if (g == 0) {
        float* sp = isq
            ? &sumsq[((type * 2) * 2 + b) * C + h * 8 + ch]
            : &sumsq[((type * 2 + 1) * 2 + b) * C + h * 8 + (ch - 8)];
        atomicAdd(sp, s2);
    }
}

// ---------------------------------------------------------------------------
// K3: attn normalize + temp, proj conv1x1 + BN + ReLU, softmax -> a1, a2
// ---------------------------------------------------------------------------
__global__ __launch_bounds__(256) void k_fuse(
    const float* __restrict__ dot1, const float* __restrict__ dot2,
    const float* __restrict__ sumsq,
    const float* __restrict__ temp1, const float* __restrict__ temp2,
    const float* __restrict__ pw, const float* __restrict__ pb,
    const float* __restrict__ g, const float* __restrict__ be,
    const float* __restrict__ mu, const float* __restrict__ var,
    float* __restrict__ a1, float* __restrict__ a2)
{
    __shared__ float cat[128 * 64];
    __shared__ float fus[64 * 64];
    const int b = blockIdx.x;
    const int t = threadIdx.x;
    const float EPS = 1e-12f;

    for (int idx = t; idx < 128 * 64; idx += 256) {
        const int ic = idx >> 6, ij = idx & 63, i = ij >> 3, j = ij & 7;
        const int is2 = ic >> 6, h = ic & 63;
        const float* dp = is2 ? dot2 : dot1;
        const int qkk = is2 * 2, kkk = is2 * 2 + 1;
        const float nq = sqrtf(sumsq[(qkk * 2 + b) * C + h * 8 + i]);
        const float nk = sqrtf(sumsq[(kkk * 2 + b) * C + h * 8 + j]);
        const float tv = is2 ? temp2[h] : temp1[h];
        const float d = dp[((size_t)(b * HEADS + h) << 6) + ij];
        cat[idx] = d / (fmaxf(nq, EPS) * fmaxf(nk, EPS)) * tv;
    }
    __syncthreads();

    for (int idx = t; idx < 64 * 64; idx += 256) {
        const int hd = idx >> 6, ij = idx & 63;
        float acc = pb[hd];
        for (int ic = 0; ic < 128; ++ic)
            acc += pw[hd * 128 + ic] * cat[ic * 64 + ij];
        const float sc = g[hd] / sqrtf(var[hd] + 1e-5f);
        const float v = (acc - mu[hd]) * sc + be[hd];
        fus[idx] = fmaxf(v, 0.f);
    }
    __syncthreads();

    for (int r = t; r < 512; r += 256) {
        const int hd = r >> 3, i = r & 7;
        float v[8], mx, sum;
        mx = -1e30f;
        #pragma unroll
        for (int j = 0; j < 8; ++j) { v[j] = fus[(hd << 6) + i * 8 + j] + cat[(hd << 6) + i * 8 + j]; mx = fmaxf(mx, v[j]); }
        sum = 0.f;
        #pragma unroll
        for (int j = 0; j < 8; ++j) { v[j] = __expf(v[j] - mx); sum += v[j]; }
        #pragma unroll
        for (int j = 0; j < 8; ++j) a1[((size_t)(b * HEADS + hd) << 6) + i * 8 + j] = v[j] / sum;
        mx = -1e30f;
        #pragma unroll
        for (int j = 0; j < 8; ++j) { v[j] = fus[(hd << 6) + i * 8 + j] + cat[((64 + hd) << 6) + i * 8 + j]; mx = fmaxf(mx, v[j]); }
        sum = 0.f;
        #pragma unroll
        for (int j = 0; j < 8; ++j) { v[j] = __expf(v[j] - mx); sum += v[j]; }
        #pragma unroll
        for (int j = 0; j < 8; ++j) a2[((size_t)(b * HEADS + hd) << 6) + i * 8 + j] = v[j] / sum;
    }
}

// ---------------------------------------------------------------------------
// K4: output. Fold the +v identity into A (A' = A + I), stream one conv
// channel at a time into o[8][8]. v-plane addressing parameterized for the
// merged slab layout (vstride in shorts per zb, vrowoff channel offset).
// ---------------------------------------------------------------------------
__global__ __launch_bounds__(256) void k_out(
    const short* __restrict__ vslab, long long vstride, int vrowoff,
    const float* __restrict__ hsi, const float* __restrict__ lidar,
    const float* __restrict__ dwh_w, const float* __restrict__ dwh_b,
    const float* __restrict__ dwl_w, const float* __restrict__ dwl_b,
    const float* __restrict__ a1, const float* __restrict__ a2,
    float* __restrict__ out)
{
    __shared__ float A[64];          // A' = A + I
    __shared__ float wv[72], bvs[8];
    const int chunk = blockIdx.x, h = blockIdx.y, zb = blockIdx.z;
    const int s = zb >> 1, b = zb & 1;
    const int t = threadIdx.x;

    const float* x   = (s ? lidar : hsi) + (size_t)b * C * HW;
    const float* dww = s ? dwl_w : dwh_w;
    const float* dwb = s ? dwl_b : dwh_b;
    const float* Ag  = (s ? a2 : a1) + ((size_t)(b * HEADS + h) << 6);
    if (t < 64) A[t] = Ag[t] + (((t >> 3) == (t & 7)) ? 1.0f : 0.0f);
    if (t < 72) wv[t] = dww[(2 * C + h * 8) * 9 + t];
    if (t < 8)  bvs[t] = dwb[2 * C + h * 8 + t];
    __syncthreads();

    const int lane = t & 63, cg = t & 15;
    const int row = chunk * 16 + (t >> 4);
    const int col0 = cg << 3;

    const short* ybase = vslab + (size_t)zb * (size_t)vstride
                       + (size_t)(vrowoff + h * 8) * HW + col0;
    const float* xbase = x + (size_t)(h * 8) * HW + (size_t)row * WW + col0;
    float* obase = out + ((size_t)((s * B2 + b) * C + h * 8)) * HW + (size_t)row * WW + col0;

    float o[8][8];
    #pragma unroll
    for (int i = 0; i < 8; ++i)
        #pragma unroll
        for (int px = 0; px < 8; ++px) o[i][px] = 0.f;

    #pragma unroll
    for (int d = 0; d < 8; ++d) {
        float vd[8];
        conv8(ybase + (size_t)d * HW, row, lane, cg, wv + d * 9, bvs[d], vd);
        #pragma unroll
        for (int i = 0; i < 8; ++i) {
            const float ad = A[i * 8 + d];
            #pragma unroll
            for (int px = 0; px < 8; ++px) o[i][px] += ad * vd[px];
        }
    }

    #pragma unroll
    for (int i = 0; i < 8; ++i) {
        f32x4 x0 = *(const f32x4*)(xbase + (size_t)i * HW);
        f32x4 x1 = *(const f32x4*)(xbase + (size_t)i * HW + 4);
        f32x4 o0 = { o[i][0] + x0[0], o[i][1] + x0[1], o[i][2] + x0[2], o[i][3] + x0[3] };
        f32x4 o1 = { o[i][4] + x1[0], o[i][5] + x1[1], o[i][6] + x1[2], o[i][7] + x1[3] };
        *(f32x4*)(obase + (size_t)i * HW)     = o0;
        *(f32x4*)(obase + (size_t)i * HW + 4) = o1;
    }
}

// ---------------------------------------------------------------------------
extern "C" void kernel_launch(void* const* d_in, const int* in_sizes, int n_in,
                              void* d_out, int out_size, void* d_ws, size_t ws_size,
                              hipStream_t stream)
{
    const float* hsi  = (const float*)d_in[0];
    const float* lidar= (const float*)d_in[1];
    const float* hqw  = (const float*)d_in[2];
    const float* hqb  = (const float*)d_in[3];
    const float* lqw  = (const float*)d_in[4];
    const float* lqb  = (const float*)d_in[5];
    const float* hdw  = (const float*)d_in[6];
    const float* hdb  = (const float*)d_in[7];
    const float* ldw  = (const float*)d_in[8];
    const float* ldb  = (const float*)d_in[9];
    const float* t1   = (const float*)d_in[10];
    const float* t2   = (const float*)d_in[11];
    const float* pw   = (const float*)d_in[12];
    const float* pb   = (const float*)d_in[13];
    const float* bg   = (const float*)d_in[14];
    const float* bb   = (const float*)d_in[15];
    const float* bm   = (const float*)d_in[16];
    const float* bvv  = (const float*)d_in[17];

    // Workspace: [0,147456) fp32 stats; slab after that.
    char* ws = (char*)d_ws;
    float* dot1  = (float*)ws;                               // [2][64][8][8]
    float* dot2  = dot1 + 2 * HEADS * 64;
    float* sumsq = dot2 + 2 * HEADS * 64;                    // [4][2][512]
    float* a1    = sumsq + 4 * 2 * C;
    float* a2    = a1 + 2 * HEADS * 64;
    short* slab  = (short*)(ws + 147456);

    const size_t statbytes = (size_t)(2 * HEADS * 64 * 2 + 4 * 2 * C) * sizeof(float);
    hipMemsetAsync(dot1, 0, statbytes, stream);

    const size_t planeBytes  = (size_t)C * HW * sizeof(short);     // 16.8 MB
    const size_t imgBytes    = 3 * planeBytes;                     // 50.3 MB (q,k,v)
    const size_t needMerged  = 147456 + 4 * imgBytes;              // ~201.5 MB
    const size_t needR3      = 147456 + 8 * planeBytes;            // ~134.4 MB

    const size_t imgS = (size_t)3 * C * HW;   // shorts per image in merged slab

    if (ws_size >= needMerged) {
        // ---- Merged q/k/v path: each image read ONCE, 1536 output rows.
        // img = modality*2 + batch; rows [0,512)=q, [512,1024)=k, [1024,1536)=v.
        GemmJobs jj;
        const float* imgs[4] = { hsi, hsi + (size_t)C * HW, lidar, lidar + (size_t)C * HW };
        const float* wms[4]  = { hqw, hqw, lqw, lqw };
        const float* bs[4]   = { hqb, hqb, lqb, lqb };
        for (int img = 0; img < 4; ++img)
            jj.j[img] = { imgs[img], wms[img], bs[img], slab + (size_t)img * imgS, 0 };
        for (int i = 4; i < 8; ++i) jj.j[i] = jj.j[0];
        k_gemm<<<dim3(12, 128, 4), 256, 0, stream>>>(jj);

        StatsJobs sj;
        for (int job = 0; job < 4; ++job) {
            const int b = job >> 1, type = job & 1;
            sj.q[job] = slab + (size_t)(type * 2 + b) * imgS;                       // q rows
            sj.k[job] = slab + (size_t)((1 - type) * 2 + b) * imgS + (size_t)C * HW; // k rows
        }
        k_stats<<<dim3(8, 64, 4), 256, 0, stream>>>(
            sj, hdw, hdb, ldw, ldb, dot1, dot2, sumsq, 0);

        k_fuse<<<dim3(2, 1, 1), 256, 0, stream>>>(dot1, dot2, sumsq, t1, t2,
                                                  pw, pb, bg, bb, bm, bvv, a1, a2);
        k_out<<<dim3(8, 64, 4), 256, 0, stream>>>(
            slab, (long long)imgS, 2 * C, hsi, lidar,
            hdw, hdb, ldw, ldb, a1, a2, (float*)d_out);
    } else if (ws_size >= needR3) {
        // ---- R3 path (separate qk jobs + v pass), ~134 MB ----
        GemmJobs jj;
        for (int job = 0; job < 4; ++job) {
            const int b = job >> 1, type = job & 1;
            const float* qx = (type ? lidar : hsi) + (size_t)b * C * HW;
            const float* kx = (type ? hsi : lidar) + (size_t)b * C * HW;
            const float* qw = type ? lqw : hqw;  const float* qb = type ? lqb : hqb;
            const float* kw = type ? hqw : lqw;  const float* kb = type ? hqb : lqb;
            jj.j[2 * job]     = { qx, qw, qb, slab + (size_t)(2 * job) * C * HW,     0 };
            jj.j[2 * job + 1] = { kx, kw, kb, slab + (size_t)(2 * job + 1) * C * HW, C };
        }
        k_gemm<<<dim3(4, 128, 8), 256, 0, stream>>>(jj);

        StatsJobs sj;
        for (int job = 0; job < 4; ++job) {
            sj.q[job] = slab + (size_t)(2 * job) * C * HW;
            sj.k[job] = slab + (size_t)(2 * job + 1) * C * HW;
        }
        k_stats<<<dim3(8, 64, 4), 256, 0, stream>>>(
            sj, hdw, hdb, ldw, ldb, dot1, dot2, sumsq, 0);

        GemmJobs vj;
        vj.j[0] = { hsi,                    hqw, hqb, slab,                      2 * C };
        vj.j[1] = { hsi   + (size_t)C * HW, hqw, hqb, slab + (size_t)C * HW,     2 * C };
        vj.j[2] = { lidar,                  lqw, lqb, slab + (size_t)2 * C * HW, 2 * C };
        vj.j[3] = { lidar + (size_t)C * HW, lqw, lqb, slab + (size_t)3 * C * HW, 2 * C };
        for (int i = 4; i < 8; ++i) vj.j[i] = vj.j[0];
        k_gemm<<<dim3(4, 128, 4), 256, 0, stream>>>(vj);

        k_fuse<<<dim3(2, 1, 1), 256, 0, stream>>>(dot1, dot2, sumsq, t1, t2,
                                                  pw, pb, bg, bb, bm, bvv, a1, a2);
        k_out<<<dim3(8, 64, 4), 256, 0, stream>>>(
            slab, (long long)((size_t)C * HW), 0, hsi, lidar,
            hdw, hdb, ldw, ldb, a1, a2, (float*)d_out);
    } else {
        // ---- Small-ws fallback (~67 MB): sequential per (b,type) ----
        for (int b = 0; b < 2; ++b) {
            for (int type = 0; type < 2; ++type) {
                const float* qx = (type ? lidar : hsi) + (size_t)b * C * HW;
                const float* kx = (type ? hsi : lidar) + (size_t)b * C * HW;
                const float* qw = type ? lqw : hqw;  const float* qb = type ? lqb : hqb;
                const float* kw = type ? hqw : lqw;  const float* kb = type ? hqb : lqb;
                GemmJobs jj;
                jj.j[0] = { qx, qw, qb, slab,                  0 };
                jj.j[1] = { kx, kw, kb, slab + (size_t)C * HW, C };
                for (int i = 2; i < 8; ++i) jj.j[i] = jj.j[0];
                k_gemm<<<dim3(4, 128, 2), 256, 0, stream>>>(jj);
                StatsJobs sj;
                sj.q[0] = slab;
                sj.k[0] = slab + (size_t)C * HW;
                for (int i = 1; i < 4; ++i) { sj.q[i] = sj.q[0]; sj.k[i] = sj.k[0]; }
                k_stats<<<dim3(8, 64, 1), 256, 0, stream>>>(
                    sj, hdw, hdb, ldw, ldb, dot1, dot2, sumsq, b * 2 + type);
            }
        }
        GemmJobs vj;
        vj.j[0] = { hsi,                    hqw, hqb, slab,                      2 * C };
        vj.j[1] = { hsi   + (size_t)C * HW, hqw, hqb, slab + (size_t)C * HW,     2 * C };
        vj.j[2] = { lidar,                  lqw, lqb, slab + (size_t)2 * C * HW, 2 * C };
        vj.j[3] = { lidar + (size_t)C * HW, lqw, lqb, slab + (size_t)3 * C * HW, 2 * C };
        for (int i = 4; i < 8; ++i) vj.j[i] = vj.j[0];
        k_gemm<<<dim3(4, 128, 4), 256, 0, stream>>>(vj);

        k_fuse<<<dim3(2, 1, 1), 256, 0, stream>>>(dot1, dot2, sumsq, t1, t2,
                                                  pw, pb, bg, bb, bm, bvv, a1, a2);
        k_out<<<dim3(8, 64, 4), 256, 0, stream>>>(
            slab, (long long)((size_t)C * HW), 0, hsi, lidar,
            hdw, hdb, ldw, ldb, a1, a2, (float*)d_out);
    }
}

// Round 6
// 763.383 us; speedup vs baseline: 1.6999x; 1.1056x over previous
//
#include <hip/hip_runtime.h>
#include <hip/hip_bf16.h>

// Problem constants
#define B2    2
#define C     512
#define HH    128
#define WW    128
#define HW    16384
#define HEADS 64

typedef __attribute__((ext_vector_type(8))) short bf16x8;
typedef __attribute__((ext_vector_type(4))) float f32x4;
typedef __attribute__((ext_vector_type(4))) unsigned u32x4;

__device__ __forceinline__ float b2f(short s) {
    union { unsigned u; float f; } x;
    x.u = ((unsigned)(unsigned short)s) << 16;
    return x.f;
}
// Integer RNE (used only in low-frequency epilogue paths).
__device__ __forceinline__ short f2b(float f) {
    unsigned u; __builtin_memcpy(&u, &f, 4);
    unsigned r = u + 0x7FFFu + ((u >> 16) & 1u);   // RNE
    return (short)(r >> 16);
}
// HW packed conversion: 2 f32 -> 1 dword of 2 bf16 (RNE), one VALU op.
__device__ __forceinline__ unsigned cvt_pk(float lo, float hi) {
    unsigned r;
    asm("v_cvt_pk_bf16_f32 %0, %1, %2" : "=v"(r) : "v"(lo), "v"(hi));
    return r;
}

// ---------------------------------------------------------------------------
// Vectorized 3x3 depthwise conv for one channel, 8 consecutive pixels/thread.
// (Used by k_out.)
// ---------------------------------------------------------------------------
__device__ __forceinline__ void conv8(
    const short* __restrict__ plane, int row, int lane, int cg,
    const float* __restrict__ w9, float bias0, float* o)
{
    #pragma unroll
    for (int i = 0; i < 8; ++i) o[i] = bias0;
    #pragma unroll
    for (int dr = 0; dr < 3; ++dr) {
        const int r2 = row + dr - 1;
        const bool ok = (unsigned)r2 < (unsigned)HH;
        bf16x8 v = {0, 0, 0, 0, 0, 0, 0, 0};
        if (ok) v = *(const bf16x8*)(plane + (size_t)r2 * WW);
        float rv[10];
        #pragma unroll
        for (int j = 0; j < 8; ++j) rv[1 + j] = b2f(v[j]);
        const float lf = __shfl(rv[8], lane - 1);   // neighbor's col0+7 = my col0-1
        const float rt = __shfl(rv[1], lane + 1);   // neighbor's col0   = my col0+8
        rv[0] = (cg == 0)  ? 0.f : lf;
        rv[9] = (cg == 15) ? 0.f : rt;
        const float w0 = w9[dr * 3], w1 = w9[dr * 3 + 1], w2 = w9[dr * 3 + 2];
        #pragma unroll
        for (int i = 0; i < 8; ++i)
            o[i] += w0 * rv[i] + w1 * rv[i + 1] + w2 * rv[i + 2];
    }
}

// ---------------------------------------------------------------------------
// K0 (R5): fp32 -> bf16 conversion pass (RNE, identical rounding to the
// in-loop conversion it replaces). Grid-stride over 8-float groups.
// ---------------------------------------------------------------------------
struct CvtJobs { const float* src[4]; short* dst[4]; int n8[4]; };

__global__ __launch_bounds__(256) void k_cvt(CvtJobs cj)
{
    const int z = blockIdx.z;
    const float* __restrict__ src = cj.src[z];
    unsigned* __restrict__ dst = (unsigned*)cj.dst[z];
    const int n8 = cj.n8[z];
    for (int i = blockIdx.x * 256 + threadIdx.x; i < n8; i += gridDim.x * 256) {
        f32x4 v0 = *(const f32x4*)(src + (size_t)i * 8);
        f32x4 v1 = *(const f32x4*)(src + (size_t)i * 8 + 4);
        u32x4 o = { cvt_pk(v0[0], v0[1]), cvt_pk(v0[2], v0[3]),
                    cvt_pk(v1[0], v1[1]), cvt_pk(v1[2], v1[3]) };
        *(u32x4*)(dst + (size_t)i * 4) = o;
    }
}

// ---------------------------------------------------------------------------
// GEMM tile parameters
// ---------------------------------------------------------------------------
#define BM 128
#define BN 128
#define BK 32
#define LDK 40

// ---------------------------------------------------------------------------
// K1 (R5): bf16-source GEMM. A (weights) and B (image) pre-converted to
// bf16 by k_cvt. Per thread-step: A = 2x16B loads, B = 8 coalesced dword
// loads (dword = 2 adjacent px, same k) + bit-pack -> 2 b128 LDS writes.
// Register prefetch: next step's loads issue right after barrier 1, hiding
// HBM latency under ds_read+MFMA (T3 minimum 2-phase, reg-staged).
// Bs rows are written in (2pp, 2pp+1) pairs at 160B stride -> 16-way bank
// conflict if linear; XOR swizzle byte ^= ((row>>3)&7)<<4 applied at BOTH
// write and read spreads the mod-8 row groups over 8 distinct 16B slots.
// ---------------------------------------------------------------------------
struct G2Job  { const short* Xb; const short* Wb; const float* bias; short* Y; };
struct G2Jobs { G2Job j[2]; };

__global__ __launch_bounds__(256) void k_gemm2(G2Jobs jobs)
{
    __shared__ __align__(16) short As[BM * LDK];
    __shared__ __align__(16) short Bs[BN * LDK];

    // XCD-aware bijective remap (nwg divisible by 8).
    unsigned bx = blockIdx.x, by = blockIdx.y, bz = blockIdx.z;
    {
        const unsigned nx = gridDim.x, ny = gridDim.y, nz = gridDim.z;
        const unsigned nwg = nx * ny * nz;
        if ((nwg & 7u) == 0u) {
            const unsigned hw = bx + nx * (by + ny * bz);
            const unsigned lid = (hw & 7u) * (nwg >> 3) + (hw >> 3);
            bx = lid % nx;
            const unsigned rest = lid / nx;
            by = rest % ny;
            bz = rest / ny;
        }
    }

    const G2Job jb = jobs.j[bz];
    const short* __restrict__ Xb = jb.Xb;
    const short* __restrict__ Wb = jb.Wb;
    const float* __restrict__ bias = jb.bias;
    short* __restrict__ Y = jb.Y;

    const int co0 = bx * BM;
    const int p0  = by * BN;

    const int t = threadIdx.x;
    const int lane = t & 63, wv = t >> 6;
    const int wm = (wv & 1) << 6, wn = (wv >> 1) << 6;
    const int l15 = lane & 15, quad = lane >> 4;
    const int rm  = t & 127;
    const int kcA = (t >> 7) << 4;      // 0 or 16
    const int pp  = t & 63;             // pixel-pair index
    const int ksB = (t >> 6) << 3;      // 0,8,16,24

    const short* aptr = Wb + (size_t)(co0 + rm) * C + kcA;
    const unsigned* xptr = (const unsigned*)Xb + (size_t)ksB * (HW / 2)
                         + (p0 >> 1) + pp;

    // Prologue: load kk=0 into regs.
    bf16x8 a0 = *(const bf16x8*)aptr;
    bf16x8 a1 = *(const bf16x8*)(aptr + 8);
    unsigned bd[8];
    #pragma unroll
    for (int i = 0; i < 8; ++i) bd[i] = xptr[(size_t)i * (HW / 2)];

    f32x4 acc[4][4] = {};

    for (int kk = 0; kk < C; kk += BK) {
        // Stage current regs -> LDS.
        *(bf16x8*)&As[rm * LDK + kcA]     = a0;
        *(bf16x8*)&As[rm * LDK + kcA + 8] = a1;
        unsigned lo[4], hi[4];
        #pragma unroll
        for (int j = 0; j < 4; ++j) {
            lo[j] = (bd[2 * j] & 0xFFFFu) | (bd[2 * j + 1] << 16);
            hi[j] = (bd[2 * j] >> 16) | (bd[2 * j + 1] & 0xFFFF0000u);
        }
        {
            const int r0 = 2 * pp, r1 = 2 * pp + 1;
            const unsigned off0 = (unsigned)((r0 * LDK + ksB) * 2) ^ ((((unsigned)r0 >> 3) & 7u) << 4);
            const unsigned off1 = (unsigned)((r1 * LDK + ksB) * 2) ^ ((((unsigned)r1 >> 3) & 7u) << 4);
            u32x4 wlo = { lo[0], lo[1], lo[2], lo[3] };
            u32x4 whi = { hi[0], hi[1], hi[2], hi[3] };
            *(u32x4*)((char*)Bs + off0) = wlo;
            *(u32x4*)((char*)Bs + off1) = whi;
        }
        __syncthreads();

        // Prefetch next K-step into regs (overlaps ds_read + MFMA below).
        if (kk + BK < C) {
            a0 = *(const bf16x8*)(aptr + kk + BK);
            a1 = *(const bf16x8*)(aptr + kk + BK + 8);
            #pragma unroll
            for (int i = 0; i < 8; ++i)
                bd[i] = xptr[(size_t)(kk + BK + i) * (HW / 2)];
        }

        bf16x8 af[4], bfr[4];
        #pragma unroll
        for (int i = 0; i < 4; ++i)
            af[i] = *(const bf16x8*)&As[(wm + i * 16 + l15) * LDK + quad * 8];
        #pragma unroll
        for (int i = 0; i < 4; ++i) {
            const int rr = wn + i * 16 + l15;
            const unsigned offr = (unsigned)((rr * LDK + quad * 8) * 2) ^ ((((unsigned)rr >> 3) & 7u) << 4);
            bfr[i] = *(const bf16x8*)((char*)Bs + offr);
        }
        #pragma unroll
        for (int i = 0; i < 4; ++i)
            #pragma unroll
            for (int j = 0; j < 4; ++j)
                acc[i][j] = __builtin_amdgcn_mfma_f32_16x16x32_bf16(af[i], bfr[j], acc[i][j], 0, 0, 0);
        __syncthreads();
    }

    #pragma unroll
    for (int i = 0; i < 4; ++i) {
        #pragma unroll
        for (int r = 0; r < 4; ++r) {
            const int co = co0 + wm + i * 16 + quad * 4 + r;
            const float bv = bias[co];
            #pragma unroll
            for (int j = 0; j < 4; ++j) {
                const int p = p0 + wn + j * 16 + l15;
                Y[(size_t)co * HW + p] = f2b(acc[i][j][r] + bv);
            }
        }
    }
}

// ---------------------------------------------------------------------------
// K1-legacy: fp32-source GEMM (R4) for fallback workspace tiers.
// ---------------------------------------------------------------------------
struct GemmJob  { const float* X; const float* W; const float* bias; short* Y; int co_off; };
struct GemmJobs { GemmJob j[8]; };

__global__ __launch_bounds__(256) void k_gemm(GemmJobs jobs)
{
    __shared__ __align__(16) short As[BM * LDK];
    __shared__ __align__(16) short Bs[BN * LDK];

    unsigned bx = blockIdx.x, by = blockIdx.y, bz = blockIdx.z;
    {
        const unsigned nx = gridDim.x, ny = gridDim.y, nz = gridDim.z;
        const unsigned nwg = nx * ny * nz;
        if ((nwg & 7u) == 0u) {
            const unsigned hw = bx + nx * (by + ny * bz);
            const unsigned lid = (hw & 7u) * (nwg >> 3) + (hw >> 3);
            bx = lid % nx;
            const unsigned rest = lid / nx;
            by = rest % ny;
            bz = rest / ny;
        }
    }

    const GemmJob jb = jobs.j[bz];
    const float* X    = jb.X;
    const float* Wm   = jb.W;
    const float* bias = jb.bias;
    short*       Y    = jb.Y;
    const int co_off  = jb.co_off;

    const int co0 = bx * BM;
    const int p0  = by * BN;

    const int t = threadIdx.x;
    const int lane = t & 63, wv = t >> 6;
    const int wm = (wv & 1) << 6, wn = (wv >> 1) << 6;
    const int l15 = lane & 15, quad = lane >> 4;
    const int rm = t & 127;
    const int kc = (t >> 7) << 4;

    f32x4 acc[4][4] = {};

    for (int kk = 0; kk < C; kk += BK) {
        const float* asrc = Wm + (size_t)(co_off + co0 + rm) * C + kk + kc;
        unsigned au[4];
        #pragma unroll
        for (int j = 0; j < 2; ++j) {
            f32x4 v = *(const f32x4*)(asrc + j * 4);
            au[2 * j]     = cvt_pk(v[0], v[1]);
            au[2 * j + 1] = cvt_pk(v[2], v[3]);
        }
        unsigned au2[4];
        #pragma unroll
        for (int j = 0; j < 2; ++j) {
            f32x4 v = *(const f32x4*)(asrc + 8 + j * 4);
            au2[2 * j]     = cvt_pk(v[0], v[1]);
            au2[2 * j + 1] = cvt_pk(v[2], v[3]);
        }
        const float* bsrc = X + (size_t)(kk + kc) * HW + p0 + rm;
        float bv[16];
        #pragma unroll
        for (int j = 0; j < 16; ++j) bv[j] = bsrc[(size_t)j * HW];
        unsigned bu[8];
        #pragma unroll
        for (int j = 0; j < 8; ++j) bu[j] = cvt_pk(bv[2 * j], bv[2 * j + 1]);

        *(u32x4*)&As[rm * LDK + kc]     = *(const u32x4*)au;
        *(u32x4*)&As[rm * LDK + kc + 8] = *(const u32x4*)au2;
        *(u32x4*)&Bs[rm * LDK + kc]     = *(const u32x4*)bu;
        *(u32x4*)&Bs[rm * LDK + kc + 8] = *(const u32x4*)(bu + 4);
        __syncthreads();

        bf16x8 af[4], bfr[4];
        #pragma unroll
        for (int i = 0; i < 4; ++i)
            af[i]  = *(const bf16x8*)&As[(wm + i * 16 + l15) * LDK + quad * 8];
        #pragma unroll
        for (int i = 0; i < 4; ++i)
            bfr[i] = *(const bf16x8*)&Bs[(wn + i * 16 + l15) * LDK + quad * 8];
        #pragma unroll
        for (int i = 0; i < 4; ++i)
            #pragma unroll
            for (int j = 0; j < 4; ++j)
                acc[i][j] = __builtin_amdgcn_mfma_f32_16x16x32_bf16(af[i], bfr[j], acc[i][j], 0, 0, 0);
        __syncthreads();
    }

    #pragma unroll
    for (int i = 0; i < 4; ++i) {
        #pragma unroll
        for (int r = 0; r < 4; ++r) {
            const int co = co0 + wm + i * 16 + quad * 4 + r;
            const float bv = bias[co_off + co];
            #pragma unroll
            for (int j = 0; j < 4; ++j) {
                const int p = p0 + wn + j * 16 + l15;
                Y[(size_t)co * HW + p] = f2b(acc[i][j][r] + bv);
            }
        }
    }
}

// ---------------------------------------------------------------------------
// K2: Gram matrix via MFMA (R3 structure, R4 parameterization).
// ---------------------------------------------------------------------------
struct StatsJobs { const short* q[4]; const short* k[4]; };

__global__ __launch_bounds__(256) void k_stats(
    StatsJobs sj,
    const float* __restrict__ dwh_w, const float* __restrict__ dwh_b,
    const float* __restrict__ dwl_w, const float* __restrict__ dwl_b,
    float* __restrict__ dot1, float* __restrict__ dot2, float* __restrict__ sumsq,
    int job0)
{
    const int chunk = blockIdx.x;     // 8 chunks of 16 rows
    const int h = blockIdx.y;
    const int z = blockIdx.z;
    const int job = job0 + z;
    const int b = job >> 1, type = job & 1;

    const int t = threadIdx.x;
    const int lane = t & 63, w = t >> 6;
    const int ch = lane & 15, g = lane >> 4;
    const bool isq = (ch < 8);

    const float* dw = isq ? (type ? dwl_w : dwh_w) : (type ? dwh_w : dwl_w);
    const float* db = isq ? (type ? dwl_b : dwh_b) : (type ? dwh_b : dwl_b);
    const int crow = isq ? (h * 8 + ch) : (C + h * 8 + ch - 8);
    float w9[9];
    #pragma unroll
    for (int i = 0; i < 9; ++i) w9[i] = dw[crow * 9 + i];
    const float bias0 = db[crow];

    const short* plane = isq ? (sj.q[z] + (size_t)(h * 8 + ch) * HW)
                             : (sj.k[z] + (size_t)(h * 8 + (ch - 8)) * HW);

    f32x4 acc = {0.f, 0.f, 0.f, 0.f};
    float s2 = 0.f;

    for (int cr = 0; cr < 4; ++cr) {
        const int row = chunk * 16 + w * 4 + cr;
        #pragma unroll
        for (int cc = 0; cc < 4; ++cc) {
            const int px0 = cc * 32 + g * 8;
            float o[8];
            #pragma unroll
            for (int i = 0; i < 8; ++i) o[i] = bias0;
            #pragma unroll
            for (int dr = 0; dr < 3; ++dr) {
                const int r2 = row + dr - 1;
                const bool ok = (unsigned)r2 < (unsigned)HH;
                const short* rp = plane + (size_t)r2 * WW;
                bf16x8 v = {0, 0, 0, 0, 0, 0, 0, 0};
                short sl = 0, sr = 0;
                if (ok) {
                    v = *(const bf16x8*)(rp + px0);
                    if (px0 > 0)      sl = rp[px0 - 1];
                    if (px0 + 8 < WW) sr = rp[px0 + 8];
                }
                float rv[10];
                rv[0] = b2f(sl); rv[9] = b2f(sr);
                #pragma unroll
                for (int j = 0; j < 8; ++j) rv[1 + j] = b2f(v[j]);
                const float w0 = w9[dr * 3], w1 = w9[dr * 3 + 1], w2 = w9[dr * 3 + 2];
                #pragma unroll
                for (int i = 0; i < 8; ++i)
                    o[i] += w0 * rv[i] + w1 * rv[i + 1] + w2 * rv[i + 2];
            }
            #pragma unroll
            for (int i = 0; i < 8; ++i) s2 += o[i] * o[i];
            unsigned pu[4];
            #pragma unroll
            for (int p = 0; p < 4; ++p) pu[p] = cvt_pk(o[2 * p], o[2 * p + 1]);
            bf16x8 f; __builtin_memcpy(&f, pu, 16);
            acc = __builtin_amdgcn_mfma_f32_16x16x32_bf16(f, f, acc, 0, 0, 0);
        }
    }

    float* dotp = (type ? dot2 : dot1) + ((size_t)(b * HEADS + h) << 6);
    #pragma unroll
    for (int r = 0; r < 4; ++r) {
        const int rowc = g * 4 + r;
        if (rowc < 8 && ch >= 8)
            atomicAdd(&dotp[rowc * 8 + (ch - 8)], acc[r]);
    }
    s2 += __shfl_down(s2, 32);
    s2 += __shfl_down(s2, 16);
    if (g == 0) {
        float* sp = isq
            ? &sumsq[((type * 2) * 2 + b) * C + h * 8 + ch]
            : &sumsq[((type * 2 + 1) * 2 + b) * C + h * 8 + (ch - 8)];
        atomicAdd(sp, s2);
    }
}

// ---------------------------------------------------------------------------
// K3: attn normalize + temp, proj conv1x1 + BN + ReLU, softmax -> a1, a2
// ---------------------------------------------------------------------------
__global__ __launch_bounds__(256) void k_fuse(
    const float* __restrict__ dot1, const float* __restrict__ dot2,
    const float* __restrict__ sumsq,
    const float* __restrict__ temp1, const float* __restrict__ temp2,
    const float* __restrict__ pw, const float* __restrict__ pb,
    const float* __restrict__ g, const float* __restrict__ be,
    const float* __restrict__ mu, const float* __restrict__ var,
    float* __restrict__ a1, float* __restrict__ a2)
{
    __shared__ float cat[128 * 64];
    __shared__ float fus[64 * 64];
    const int b = blockIdx.x;
    const int t = threadIdx.x;
    const float EPS = 1e-12f;

    for (int idx = t; idx < 128 * 64; idx += 256) {
        const int ic = idx >> 6, ij = idx & 63, i = ij >> 3, j = ij & 7;
        const int is2 = ic >> 6, h = ic & 63;
        const float* dp = is2 ? dot2 : dot1;
        const int qkk = is2 * 2, kkk = is2 * 2 + 1;
        const float nq = sqrtf(sumsq[(qkk * 2 + b) * C + h * 8 + i]);
        const float nk = sqrtf(sumsq[(kkk * 2 + b) * C + h * 8 + j]);
        const float tv = is2 ? temp2[h] : temp1[h];
        const float d = dp[((size_t)(b * HEADS + h) << 6) + ij];
        cat[idx] = d / (fmaxf(nq, EPS) * fmaxf(nk, EPS)) * tv;
    }
    __syncthreads();

    for (int idx = t; idx < 64 * 64; idx += 256) {
        const int hd = idx >> 6, ij = idx & 63;
        float acc = pb[hd];
        for (int ic = 0; ic < 128; ++ic)
            acc += pw[hd * 128 + ic] * cat[ic * 64 + ij];
        const float sc = g[hd] / sqrtf(var[hd] + 1e-5f);
        const float v = (acc - mu[hd]) * sc + be[hd];
        fus[idx] = fmaxf(v, 0.f);
    }
    __syncthreads();

    for (int r = t; r < 512; r += 256) {
        const int hd = r >> 3, i = r & 7;
        float v[8], mx, sum;
        mx = -1e30f;
        #pragma unroll
        for (int j = 0; j < 8; ++j) { v[j] = fus[(hd << 6) + i * 8 + j] + cat[(hd << 6) + i * 8 + j]; mx = fmaxf(mx, v[j]); }
        sum = 0.f;
        #pragma unroll
        for (int j = 0; j < 8; ++j) { v[j] = __expf(v[j] - mx); sum += v[j]; }
        #pragma unroll
        for (int j = 0; j < 8; ++j) a1[((size_t)(b * HEADS + hd) << 6) + i * 8 + j] = v[j] / sum;
        mx = -1e30f;
        #pragma unroll
        for (int j = 0; j < 8; ++j) { v[j] = fus[(hd << 6) + i * 8 + j] + cat[((64 + hd) << 6) + i * 8 + j]; mx = fmaxf(mx, v[j]); }
        sum = 0.f;
        #pragma unroll
        for (int j = 0; j < 8; ++j) { v[j] = __expf(v[j] - mx); sum += v[j]; }
        #pragma unroll
        for (int j = 0; j < 8; ++j) a2[((size_t)(b * HEADS + hd) << 6) + i * 8 + j] = v[j] / sum;
    }
}

// ---------------------------------------------------------------------------
// K4: output. A' = A + I, stream conv channels into o[8][8].
// ---------------------------------------------------------------------------
__global__ __launch_bounds__(256) void k_out(
    const short* __restrict__ vslab, long long vstride, int vrowoff,
    const float* __restrict__ hsi, const float* __restrict__ lidar,
    const float* __restrict__ dwh_w, const float* __restrict__ dwh_b,
    const float* __restrict__ dwl_w, const float* __restrict__ dwl_b,
    const float* __restrict__ a1, const float* __restrict__ a2,
    float* __restrict__ out)
{
    __shared__ float A[64];          // A' = A + I
    __shared__ float wv[72], bvs[8];
    const int chunk = blockIdx.x, h = blockIdx.y, zb = blockIdx.z;
    const int s = zb >> 1, b = zb & 1;
    const int t = threadIdx.x;

    const float* x   = (s ? lidar : hsi) + (size_t)b * C * HW;
    const float* dww = s ? dwl_w : dwh_w;
    const float* dwb = s ? dwl_b : dwh_b;
    const float* Ag  = (s ? a2 : a1) + ((size_t)(b * HEADS + h) << 6);
    if (t < 64) A[t] = Ag[t] + (((t >> 3) == (t & 7)) ? 1.0f : 0.0f);
    if (t < 72) wv[t] = dww[(2 * C + h * 8) * 9 + t];
    if (t < 8)  bvs[t] = dwb[2 * C + h * 8 + t];
    __syncthreads();

    const int lane = t & 63, cg = t & 15;
    const int row = chunk * 16 + (t >> 4);
    const int col0 = cg << 3;

    const short* ybase = vslab + (size_t)zb * (size_t)vstride
                       + (size_t)(vrowoff + h * 8) * HW + col0;
    const float* xbase = x + (size_t)(h * 8) * HW + (size_t)row * WW + col0;
    float* obase = out + ((size_t)((s * B2 + b) * C + h * 8)) * HW + (size_t)row * WW + col0;

    float o[8][8];
    #pragma unroll
    for (int i = 0; i < 8; ++i)
        #pragma unroll
        for (int px = 0; px < 8; ++px) o[i][px] = 0.f;

    #pragma unroll
    for (int d = 0; d < 8; ++d) {
        float vd[8];
        conv8(ybase + (size_t)d * HW, row, lane, cg, wv + d * 9, bvs[d], vd);
        #pragma unroll
        for (int i = 0; i < 8; ++i) {
            const float ad = A[i * 8 + d];
            #pragma unroll
            for (int px = 0; px < 8; ++px) o[i][px] += ad * vd[px];
        }
    }

    #pragma unroll
    for (int i = 0; i < 8; ++i) {
        f32x4 x0 = *(const f32x4*)(xbase + (size_t)i * HW);
        f32x4 x1 = *(const f32x4*)(xbase + (size_t)i * HW + 4);
        f32x4 o0 = { o[i][0] + x0[0], o[i][1] + x0[1], o[i][2] + x0[2], o[i][3] + x0[3] };
        f32x4 o1 = { o[i][4] + x1[0], o[i][5] + x1[1], o[i][6] + x1[2], o[i][7] + x1[3] };
        *(f32x4*)(obase + (size_t)i * HW)     = o0;
        *(f32x4*)(obase + (size_t)i * HW + 4) = o1;
    }
}

// ---------------------------------------------------------------------------
extern "C" void kernel_launch(void* const* d_in, const int* in_sizes, int n_in,
                              void* d_out, int out_size, void* d_ws, size_t ws_size,
                              hipStream_t stream)
{
    const float* hsi  = (const float*)d_in[0];
    const float* lidar= (const float*)d_in[1];
    const float* hqw  = (const float*)d_in[2];
    const float* hqb  = (const float*)d_in[3];
    const float* lqw  = (const float*)d_in[4];
    const float* lqb  = (const float*)d_in[5];
    const float* hdw  = (const float*)d_in[6];
    const float* hdb  = (const float*)d_in[7];
    const float* ldw  = (const float*)d_in[8];
    const float* ldb  = (const float*)d_in[9];
    const float* t1   = (const float*)d_in[10];
    const float* t2   = (const float*)d_in[11];
    const float* pw   = (const float*)d_in[12];
    const float* pb   = (const float*)d_in[13];
    const float* bg   = (const float*)d_in[14];
    const float* bb   = (const float*)d_in[15];
    const float* bm   = (const float*)d_in[16];
    const float* bvv  = (const float*)d_in[17];

    // Workspace: [0,147456) fp32 stats; slab after that.
    char* ws = (char*)d_ws;
    float* dot1  = (float*)ws;                               // [2][64][8][8]
    float* dot2  = dot1 + 2 * HEADS * 64;
    float* sumsq = dot2 + 2 * HEADS * 64;                    // [4][2][512]
    float* a1    = sumsq + 4 * 2 * C;
    float* a2    = a1 + 2 * HEADS * 64;
    short* slab  = (short*)(ws + 147456);

    const size_t statbytes = (size_t)(2 * HEADS * 64 * 2 + 4 * 2 * C) * sizeof(float);
    hipMemsetAsync(dot1, 0, statbytes, stream);

    const size_t planeBytes  = (size_t)C * HW * sizeof(short);     // 16.8 MB
    const size_t imgBytes    = 3 * planeBytes;                     // 50.3 MB (q,k,v)
    const size_t imgS        = (size_t)3 * C * HW;                 // shorts per image
    const size_t wbS         = (size_t)3 * C * C;                  // 786432 shorts per modality W
    const size_t xbS         = (size_t)C * HW;                     // shorts per bf16 image

    const size_t needFull    = 147456 + (4 * imgS + 2 * wbS + 2 * xbS) * sizeof(short); // ~238.2 MB
    const size_t needMerged  = 147456 + 4 * imgBytes;              // ~201.5 MB
    const size_t needR3      = 147456 + 8 * planeBytes;            // ~134.4 MB

    if (ws_size >= needFull) {
        // ---- R5 path: pre-convert to bf16, then bf16-source GEMM. ----
        short* Wbh = slab + 4 * imgS;
        short* Wbl = Wbh + wbS;
        short* Xb0 = Wbl + wbS;
        short* Xb1 = Xb0 + xbS;

        CvtJobs c1;
        c1.src[0] = hqw;                     c1.dst[0] = Wbh; c1.n8[0] = (int)(wbS / 8);
        c1.src[1] = lqw;                     c1.dst[1] = Wbl; c1.n8[1] = (int)(wbS / 8);
        c1.src[2] = hsi;                     c1.dst[2] = Xb0; c1.n8[2] = (int)(xbS / 8);
        c1.src[3] = hsi + (size_t)C * HW;    c1.dst[3] = Xb1; c1.n8[3] = (int)(xbS / 8);
        k_cvt<<<dim3(1024, 1, 4), 256, 0, stream>>>(c1);

        G2Jobs g1;
        g1.j[0] = { Xb0, Wbh, hqb, slab + 0 * imgS };
        g1.j[1] = { Xb1, Wbh, hqb, slab + 1 * imgS };
        k_gemm2<<<dim3(12, 128, 2), 256, 0, stream>>>(g1);

        CvtJobs c2;
        c2.src[0] = lidar;                   c2.dst[0] = Xb0; c2.n8[0] = (int)(xbS / 8);
        c2.src[1] = lidar + (size_t)C * HW;  c2.dst[1] = Xb1; c2.n8[1] = (int)(xbS / 8);
        c2.src[2] = hqw;                     c2.dst[2] = Wbh; c2.n8[2] = 0;
        c2.src[3] = hqw;                     c2.dst[3] = Wbh; c2.n8[3] = 0;
        k_cvt<<<dim3(1024, 1, 2), 256, 0, stream>>>(c2);

        G2Jobs g2;
        g2.j[0] = { Xb0, Wbl, lqb, slab + 2 * imgS };
        g2.j[1] = { Xb1, Wbl, lqb, slab + 3 * imgS };
        k_gemm2<<<dim3(12, 128, 2), 256, 0, stream>>>(g2);

        StatsJobs sj;
        for (int job = 0; job < 4; ++job) {
            const int b = job >> 1, type = job & 1;
            sj.q[job] = slab + (size_t)(type * 2 + b) * imgS;                        // q rows
            sj.k[job] = slab + (size_t)((1 - type) * 2 + b) * imgS + (size_t)C * HW; // k rows
        }
        k_stats<<<dim3(8, 64, 4), 256, 0, stream>>>(
            sj, hdw, hdb, ldw, ldb, dot1, dot2, sumsq, 0);

        k_fuse<<<dim3(2, 1, 1), 256, 0, stream>>>(dot1, dot2, sumsq, t1, t2,
                                                  pw, pb, bg, bb, bm, bvv, a1, a2);
        k_out<<<dim3(8, 64, 4), 256, 0, stream>>>(
            slab, (long long)imgS, 2 * C, hsi, lidar,
            hdw, hdb, ldw, ldb, a1, a2, (float*)d_out);
    } else if (ws_size >= needMerged) {
        // ---- R4 path: merged q/k/v fp32-source GEMM. ----
        GemmJobs jj;
        const float* imgs[4] = { hsi, hsi + (size_t)C * HW, lidar, lidar + (size_t)C * HW };
        const float* wms[4]  = { hqw, hqw, lqw, lqw };
        const float* bs[4]   = { hqb, hqb, lqb, lqb };
        for (int img = 0; img < 4; ++img)
            jj.j[img] = { imgs[img], wms[img], bs[img], slab + (size_t)img * imgS, 0 };
        for (int i = 4; i < 8; ++i) jj.j[i] = jj.j[0];
        k_gemm<<<dim3(12, 128, 4), 256, 0, stream>>>(jj);

        StatsJobs sj;
        for (int job = 0; job < 4; ++job) {
            const int b = job >> 1, type = job & 1;
            sj.q[job] = slab + (size_t)(type * 2 + b) * imgS;
            sj.k[job] = slab + (size_t)((1 - type) * 2 + b) * imgS + (size_t)C * HW;
        }
        k_stats<<<dim3(8, 64, 4), 256, 0, stream>>>(
            sj, hdw, hdb, ldw, ldb, dot1, dot2, sumsq, 0);

        k_fuse<<<dim3(2, 1, 1), 256, 0, stream>>>(dot1, dot2, sumsq, t1, t2,
                                                  pw, pb, bg, bb, bm, bvv, a1, a2);
        k_out<<<dim3(8, 64, 4), 256, 0, stream>>>(
            slab, (long long)imgS, 2 * C, hsi, lidar,
            hdw, hdb, ldw, ldb, a1, a2, (float*)d_out);
    } else if (ws_size >= needR3) {
        // ---- R3 path (separate qk jobs + v pass), ~134 MB ----
        GemmJobs jj;
        for (int job = 0; job < 4; ++job) {
            const int b = job >> 1, type = job & 1;
            const float* qx = (type ? lidar : hsi) + (size_t)b * C * HW;
            const float* kx = (type ? hsi : lidar) + (size_t)b * C * HW;
            const float* qw = type ? lqw : hqw;  const float* qb = type ? lqb : hqb;
            const float* kw = type ? hqw : lqw;  const float* kb = type ? hqb : lqb;
            jj.j[2 * job]     = { qx, qw, qb, slab + (size_t)(2 * job) * C * HW,     0 };
            jj.j[2 * job + 1] = { kx, kw, kb, slab + (size_t)(2 * job + 1) * C * HW, C };
        }
        k_gemm<<<dim3(4, 128, 8), 256, 0, stream>>>(jj);

        StatsJobs sj;
        for (int job = 0; job < 4; ++job) {
            sj.q[job] = slab + (size_t)(2 * job) * C * HW;
            sj.k[job] = slab + (size_t)(2 * job + 1) * C * HW;
        }
        k_stats<<<dim3(8, 64, 4), 256, 0, stream>>>(
            sj, hdw, hdb, ldw, ldb, dot1, dot2, sumsq, 0);

        GemmJobs vj;
        vj.j[0] = { hsi,                    hqw, hqb, slab,                      2 * C };
        vj.j[1] = { hsi   + (size_t)C * HW, hqw, hqb, slab + (size_t)C * HW,     2 * C };
        vj.j[2] = { lidar,                  lqw, lqb, slab + (size_t)2 * C * HW, 2 * C };
        vj.j[3] = { lidar + (size_t)C * HW, lqw, lqb, slab + (size_t)3 * C * HW, 2 * C };
        for (int i = 4; i < 8; ++i) vj.j[i] = vj.j[0];
        k_gemm<<<dim3(4, 128, 4), 256, 0, stream>>>(vj);

        k_fuse<<<dim3(2, 1, 1), 256, 0, stream>>>(dot1, dot2, sumsq, t1, t2,
                                                  pw, pb, bg, bb, bm, bvv, a1, a2);
        k_out<<<dim3(8, 64, 4), 256, 0, stream>>>(
            slab, (long long)((size_t)C * HW), 0, hsi, lidar,
            hdw, hdb, ldw, ldb, a1, a2, (float*)d_out);
    } else {
        // ---- Small-ws fallback (~67 MB): sequential per (b,type) ----
        for (int b = 0; b < 2; ++b) {
            for (int type = 0; type < 2; ++type) {
                const float* qx = (type ? lidar : hsi) + (size_t)b * C * HW;
                const float* kx = (type ? hsi : lidar) + (size_t)b * C * HW;
                const float* qw = type ? lqw : hqw;  const float* qb = type ? lqb : hqb;
                const float* kw = type ? hqw : lqw;  const float* kb = type ? hqb : lqb;
                GemmJobs jj;
                jj.j[0] = { qx, qw, qb, slab,                  0 };
                jj.j[1] = { kx, kw, kb, slab + (size_t)C * HW, C };
                for (int i = 2; i < 8; ++i) jj.j[i] = jj.j[0];
                k_gemm<<<dim3(4, 128, 2), 256, 0, stream>>>(jj);
                StatsJobs sj;
                sj.q[0] = slab;
                sj.k[0] = slab + (size_t)C * HW;
                for (int i = 1; i < 4; ++i) { sj.q[i] = sj.q[0]; sj.k[i] = sj.k[0]; }
                k_stats<<<dim3(8, 64, 1), 256, 0, stream>>>(
                    sj, hdw, hdb, ldw, ldb, dot1, dot2, sumsq, b * 2 + type);
            }
        }
        GemmJobs vj;
        vj.j[0] = { hsi,                    hqw, hqb, slab,                      2 * C };
        vj.j[1] = { hsi   + (size_t)C * HW, hqw, hqb, slab + (size_t)C * HW,     2 * C };
        vj.j[2] = { lidar,                  lqw, lqb, slab + (size_t)2 * C * HW, 2 * C };
        vj.j[3] = { lidar + (size_t)C * HW, lqw, lqb, slab + (size_t)3 * C * HW, 2 * C };
        for (int i = 4; i < 8; ++i) vj.j[i] = vj.j[0];
        k_gemm<<<dim3(4, 128, 4), 256, 0, stream>>>(vj);

        k_fuse<<<dim3(2, 1, 1), 256, 0, stream>>>(dot1, dot2, sumsq, t1, t2,
                                                  pw, pb, bg, bb, bm, bvv, a1, a2);
        k_out<<<dim3(8, 64, 4), 256, 0, stream>>>(
            slab, (long long)((size_t)C * HW), 0, hsi, lidar,
            hdw, hdb, ldw, ldb, a1, a2, (float*)d_out);
    }
}